// Round 1
// baseline (730.494 us; speedup 1.0000x reference)
//
#include <hip/hip_runtime.h>

#define NTHREADS 256

// problem constants
constexpr int Cc   = 32;      // in channels
constexpr int Hh   = 256;     // image H=W
constexpr int FHc  = 32;      // patch grid
constexpr int PHc  = 8;       // patch size
constexpr int KHc  = 10;      // patch + halo
constexpr int HIDc = 64;
constexpr int OUTc = 32;
constexpr int R1c  = 2048;    // 64*32
constexpr int R2c  = 2624;    // + 64*9
constexpr int R3c  = 4672;    // + 32*64
constexpr float EPSc = 1e-5f;

// ws float offsets
constexpr int SLOTS1  = 0;        // 64ch * 64 slots (sum)
constexpr int SLOTS1Q = 4096;     // (sumsq)
constexpr int SLOTS2  = 8192;
constexpr int SLOTS2Q = 12288;
constexpr int SLOTS3  = 16384;    // 32ch * 64
constexpr int SLOTS3Q = 18432;
constexpr int FIN1    = 20480;    // a[64], b[64]
constexpr int FIN2    = 20608;
constexpr int FIN3    = 20736;    // a[32], b[32]
constexpr int STATS_ZERO_FLOATS = 20480;   // zero only the slot accumulators
constexpr size_t OBUF = 32768;    // float offset (128KB) for o buffer: 8192*2048 floats

// One block per patch. STAGE: how deep to compute (1,2,3).
// STORE_O: store raw stage-3 conv output to ws. WRITE_OUT: apply BN3 + residual, write output.
template<int STAGE, int STORE_O, int WRITE_OUT>
__global__ __launch_bounds__(NTHREADS)
void patch_k(const float* __restrict__ x, const float* __restrict__ s,
             float* __restrict__ ws, float* __restrict__ out) {
    __shared__ float A[5248];     // xs[3200] + w1[2048]; later z[4096] overlays
    __shared__ float Bsh[6400];   // y[6400]; later w3T[2112] + o[2048] overlay
    __shared__ float w2s[576];
    __shared__ float fin_s[256];  // a1,b1 (64+64), a2,b2 (64+64)

    const int t    = threadIdx.x;
    const int blk  = blockIdx.x;
    const int bi   = blk >> 10;
    const int f    = (blk >> 5) & 31;
    const int g    = blk & 31;
    const int slot = blk & 63;

    // ---- load patch (with reflect halo) into A[0..3199] : xs[c][10][10]
    const float* xb = x + (size_t)bi * Cc * Hh * Hh;
    for (int i = t; i < Cc * KHc * KHc; i += NTHREADS) {
        int c = i / 100;
        int rem = i - c * 100;
        int pr = rem / 10, pc = rem - pr * 10;
        int row = f * PHc - 1 + pr; row = row < 0 ? -row : (row > 255 ? 510 - row : row);
        int col = g * PHc - 1 + pc; col = col < 0 ? -col : (col > 255 ? 510 - col : col);
        A[i] = xb[(size_t)c * 65536 + row * 256 + col];
    }
    // ---- load w1 into A[3200..5247]  (w1[o][c] at A[3200 + o*32 + c])
    const float* sb = s + (size_t)bi * R3c * 1024 + f * 32 + g;
    for (int i = t; i < 2048; i += NTHREADS)
        A[3200 + i] = sb[(size_t)i * 1024];
    if (STAGE >= 2) {
        for (int i = t; i < 576; i += NTHREADS)
            w2s[i] = sb[(size_t)(R1c + i) * 1024];
        if (t < 128) fin_s[t] = ws[FIN1 + t];
        if (STAGE >= 3 && t < 128) fin_s[128 + t] = ws[FIN2 + t];
    }
    __syncthreads();

    // ---- stage 1: y[64][100] = w1 * xs   (8 ch x up-to-4 pix per thread)
    const int og = t >> 5;      // 0..7 -> channels og*8..og*8+7
    const int pl = t & 31;      // pixel lane: pix = pl, pl+32, pl+64, (pl+96)
    float acc[8][4];
    #pragma unroll
    for (int i = 0; i < 8; i++) { acc[i][0]=0.f; acc[i][1]=0.f; acc[i][2]=0.f; acc[i][3]=0.f; }
    #pragma unroll 4
    for (int c = 0; c < 32; c++) {
        float xa0 = A[c*100 + pl];
        float xa1 = A[c*100 + pl + 32];
        float xa2 = A[c*100 + pl + 64];
        float xa3 = A[c*100 + pl + 96];   // garbage when pl>=4, masked below
        const float* wrow = &A[3200 + og*256 + c];
        #pragma unroll
        for (int i = 0; i < 8; i++) {
            float wv = wrow[i*32];
            acc[i][0] += wv * xa0; acc[i][1] += wv * xa1;
            acc[i][2] += wv * xa2; acc[i][3] += wv * xa3;
        }
    }
    #pragma unroll
    for (int i = 0; i < 8; i++) {
        int ch = og*8 + i;
        Bsh[ch*100 + pl]      = acc[i][0];
        Bsh[ch*100 + pl + 32] = acc[i][1];
        Bsh[ch*100 + pl + 64] = acc[i][2];
        if (pl < 4) Bsh[ch*100 + pl + 96] = acc[i][3];
    }
    if (STAGE == 1) {
        #pragma unroll
        for (int i = 0; i < 8; i++) {
            float a3v = (pl < 4) ? acc[i][3] : 0.f;
            float sm = acc[i][0] + acc[i][1] + acc[i][2] + a3v;
            float qq = acc[i][0]*acc[i][0] + acc[i][1]*acc[i][1] + acc[i][2]*acc[i][2] + a3v*a3v;
            #pragma unroll
            for (int m = 16; m >= 1; m >>= 1) { sm += __shfl_xor(sm, m); qq += __shfl_xor(qq, m); }
            if (pl == 0) {
                atomicAdd(&ws[SLOTS1  + (og*8 + i)*64 + slot], sm);
                atomicAdd(&ws[SLOTS1Q + (og*8 + i)*64 + slot], qq);
            }
        }
        return;
    }

    __syncthreads();
    // ---- BN1 + relu6 in place on y
    for (int i = t; i < 6400; i += NTHREADS) {
        int ch = i / 100;
        float v = Bsh[i] * fin_s[ch] + fin_s[64 + ch];
        Bsh[i] = fminf(fmaxf(v, 0.f), 6.f);
    }
    // save residual x before z overlays xs
    float xres[2][4];
    if (WRITE_OUT) {
        int og3 = t >> 4, pg = t & 15;
        #pragma unroll
        for (int i = 0; i < 2; i++)
            #pragma unroll
            for (int k = 0; k < 4; k++) {
                int pix = pg*4 + k; int p = pix >> 3, q = pix & 7;
                xres[i][k] = A[(og3*2 + i)*100 + (p+1)*10 + (q+1)];
            }
    }
    __syncthreads();

    // ---- stage 2: depthwise 3x3 valid -> z[64][8][8] into A[0..4095]
    const int ch2 = t >> 2;
    const int quad = t & 3;
    const int p0 = quad * 2;
    float yr[4][10];
    #pragma unroll
    for (int r = 0; r < 4; r++)
        #pragma unroll
        for (int cc = 0; cc < 10; cc++)
            yr[r][cc] = Bsh[ch2*100 + (p0 + r)*10 + cc];
    float zacc[2][8];
    #pragma unroll
    for (int pr = 0; pr < 2; pr++)
        #pragma unroll
        for (int q = 0; q < 8; q++) zacc[pr][q] = 0.f;
    #pragma unroll
    for (int u = 0; u < 3; u++)
        #pragma unroll
        for (int v = 0; v < 3; v++) {
            float wv = w2s[ch2*9 + u*3 + v];
            #pragma unroll
            for (int pr = 0; pr < 2; pr++)
                #pragma unroll
                for (int q = 0; q < 8; q++)
                    zacc[pr][q] += wv * yr[pr + u][q + v];
        }
    float zs = 0.f, zq = 0.f;
    #pragma unroll
    for (int pr = 0; pr < 2; pr++)
        #pragma unroll
        for (int q = 0; q < 8; q++) {
            float v = zacc[pr][q];
            A[ch2*64 + (p0 + pr)*8 + q] = v;
            if (STAGE == 2) { zs += v; zq += v * v; }
        }
    if (STAGE == 2) {
        zs += __shfl_xor(zs, 1); zs += __shfl_xor(zs, 2);
        zq += __shfl_xor(zq, 1); zq += __shfl_xor(zq, 2);
        if (quad == 0) {
            atomicAdd(&ws[SLOTS2  + ch2*64 + slot], zs);
            atomicAdd(&ws[SLOTS2Q + ch2*64 + slot], zq);
        }
        return;
    }

    __syncthreads();   // z complete
    // ---- BN2 + relu6 in place on z
    for (int i = t; i < 4096; i += NTHREADS) {
        int ch = i >> 6;
        float v = A[i] * fin_s[128 + ch] + fin_s[192 + ch];
        A[i] = fminf(fmaxf(v, 0.f), 6.f);
    }
    // load w3 transposed into Bsh[0..2111]: w3T[ch*33 + oc]
    for (int i = t; i < 2048; i += NTHREADS) {
        int oc = i >> 6, ch = i & 63;
        Bsh[ch*33 + oc] = sb[(size_t)(R2c + i) * 1024];
    }
    __syncthreads();

    // ---- stage 3: o[32][64] = w3 * zn  (2 oc x 4 pix per thread)
    const int og3 = t >> 4;   // 0..15 -> oc pair og3*2, og3*2+1
    const int pg  = t & 15;   // pix pg*4 .. pg*4+3
    float o3[2][4];
    #pragma unroll
    for (int i = 0; i < 2; i++)
        #pragma unroll
        for (int k = 0; k < 4; k++) o3[i][k] = 0.f;
    #pragma unroll 4
    for (int ch = 0; ch < 64; ch++) {
        float zv0 = A[ch*64 + pg*4];
        float zv1 = A[ch*64 + pg*4 + 1];
        float zv2 = A[ch*64 + pg*4 + 2];
        float zv3 = A[ch*64 + pg*4 + 3];
        float w0 = Bsh[ch*33 + og3*2];
        float w1v = Bsh[ch*33 + og3*2 + 1];
        o3[0][0] += w0*zv0;  o3[0][1] += w0*zv1;  o3[0][2] += w0*zv2;  o3[0][3] += w0*zv3;
        o3[1][0] += w1v*zv0; o3[1][1] += w1v*zv1; o3[1][2] += w1v*zv2; o3[1][3] += w1v*zv3;
    }

    if (STAGE == 3 && !WRITE_OUT) {
        #pragma unroll
        for (int i = 0; i < 2; i++) {
            float sm = o3[i][0] + o3[i][1] + o3[i][2] + o3[i][3];
            float qq = o3[i][0]*o3[i][0] + o3[i][1]*o3[i][1] + o3[i][2]*o3[i][2] + o3[i][3]*o3[i][3];
            #pragma unroll
            for (int m = 8; m >= 1; m >>= 1) { sm += __shfl_xor(sm, m); qq += __shfl_xor(qq, m); }
            if (pg == 0) {
                atomicAdd(&ws[SLOTS3  + (og3*2 + i)*64 + slot], sm);
                atomicAdd(&ws[SLOTS3Q + (og3*2 + i)*64 + slot], qq);
            }
        }
    }
    if (STORE_O) {
        float* ob = ws + OBUF + (size_t)blk * 2048;
        #pragma unroll
        for (int i = 0; i < 2; i++)
            #pragma unroll
            for (int k = 0; k < 4; k++)
                ob[(og3*2 + i)*64 + pg*4 + k] = o3[i][k];
    }
    if (WRITE_OUT) {
        #pragma unroll
        for (int i = 0; i < 2; i++) {
            int oc = og3*2 + i;
            float a3 = ws[FIN3 + oc], b3c = ws[FIN3 + 32 + oc];
            #pragma unroll
            for (int k = 0; k < 4; k++) {
                int pix = pg*4 + k; int p = pix >> 3, q = pix & 7;
                size_t oidx = ((size_t)((bi*32 + oc)*256 + f*8 + p))*256 + g*8 + q;
                out[oidx] = xres[i][k] + o3[i][k]*a3 + b3c;
            }
        }
    }
}

__global__ void finalize_k(float* __restrict__ ws, int stage,
                           const float* __restrict__ gamma, const float* __restrict__ beta) {
    int ch = threadIdx.x;
    int nch = (stage == 3) ? 32 : 64;
    if (ch >= nch) return;
    int so = (stage == 1) ? SLOTS1  : (stage == 2) ? SLOTS2  : SLOTS3;
    int sq = (stage == 1) ? SLOTS1Q : (stage == 2) ? SLOTS2Q : SLOTS3Q;
    int fo = (stage == 1) ? FIN1    : (stage == 2) ? FIN2    : FIN3;
    float N = (stage == 1) ? 819200.0f : 524288.0f;
    float sm = 0.f, qq = 0.f;
    for (int j = 0; j < 64; j++) { sm += ws[so + ch*64 + j]; qq += ws[sq + ch*64 + j]; }
    float mean = sm / N;
    float var  = qq / N - mean * mean;
    float rstd = rsqrtf(var + EPSc);
    float a = rstd * gamma[ch];
    ws[fo + ch]       = a;
    ws[fo + nch + ch] = beta[ch] - mean * a;
}

__global__ void k4_read(const float* __restrict__ x, const float* __restrict__ ws,
                        float* __restrict__ out) {
    size_t idx = (size_t)blockIdx.x * NTHREADS + threadIdx.x;
    int wq = idx & 255;
    int h  = (idx >> 8) & 255;
    int oc = (idx >> 16) & 31;
    int bi = idx >> 21;
    float a3 = ws[FIN3 + oc], b3c = ws[FIN3 + 32 + oc];
    int fa = h >> 3, ga = wq >> 3;
    int pix = ((h & 7) << 3) | (wq & 7);
    int blk = (bi << 10) | (fa << 5) | ga;
    float o = ws[OBUF + (size_t)blk * 2048 + oc*64 + pix];
    out[idx] = x[idx] + o * a3 + b3c;
}

extern "C" void kernel_launch(void* const* d_in, const int* in_sizes, int n_in,
                              void* d_out, int out_size, void* d_ws, size_t ws_size,
                              hipStream_t stream) {
    const float* x  = (const float*)d_in[0];
    const float* s  = (const float*)d_in[1];
    const float* g1 = (const float*)d_in[2];
    const float* b1 = (const float*)d_in[3];
    const float* g2 = (const float*)d_in[4];
    const float* b2 = (const float*)d_in[5];
    const float* g3 = (const float*)d_in[6];
    const float* b3 = (const float*)d_in[7];
    float* out = (float*)d_out;
    float* ws  = (float*)d_ws;

    hipMemsetAsync(d_ws, 0, STATS_ZERO_FLOATS * sizeof(float), stream);

    const bool store_o = ws_size >= (size_t)(OBUF * 4 + (size_t)8192 * 2048 * 4);

    patch_k<1,0,0><<<8192, NTHREADS, 0, stream>>>(x, s, ws, out);
    finalize_k<<<1, 64, 0, stream>>>(ws, 1, g1, b1);
    patch_k<2,0,0><<<8192, NTHREADS, 0, stream>>>(x, s, ws, out);
    finalize_k<<<1, 64, 0, stream>>>(ws, 2, g2, b2);
    if (store_o) {
        patch_k<3,1,0><<<8192, NTHREADS, 0, stream>>>(x, s, ws, out);
        finalize_k<<<1, 64, 0, stream>>>(ws, 3, g3, b3);
        k4_read<<<65536, NTHREADS, 0, stream>>>(x, ws, out);
    } else {
        patch_k<3,0,0><<<8192, NTHREADS, 0, stream>>>(x, s, ws, out);
        finalize_k<<<1, 64, 0, stream>>>(ws, 3, g3, b3);
        patch_k<3,0,1><<<8192, NTHREADS, 0, stream>>>(x, s, ws, out);
    }
}

// Round 2
// 672.490 us; speedup vs baseline: 1.0863x; 1.0863x over previous
//
#include <hip/hip_runtime.h>

#define NTHREADS 256

// problem constants
constexpr int Cc   = 32;      // in channels
constexpr int Hh   = 256;     // image H=W
constexpr int PHc  = 8;       // patch size
constexpr int KHc  = 10;      // patch + halo
constexpr int R1c  = 2048;    // 64*32
constexpr int R2c  = 2624;    // + 64*9
constexpr int R3c  = 4672;    // + 32*64
constexpr float EPSc = 1e-5f;

// LDS padded strides (bank-conflict fixes)
constexpr int YS = 101;       // y row stride (was 100; 4-way -> 2-way)
constexpr int ZS = 65;        // z channel stride (was 64; 16-way -> 2-way)

// ws float offsets
constexpr int SLOTS1  = 0;        // 64ch * 64 slots (sum)
constexpr int SLOTS1Q = 4096;
constexpr int SLOTS2  = 8192;
constexpr int SLOTS2Q = 12288;
constexpr int SLOTS3  = 16384;    // 32ch * 64
constexpr int SLOTS3Q = 18432;
constexpr int FIN1    = 20480;    // a[64], b[64]
constexpr int FIN2    = 20608;
constexpr int FIN3    = 20736;    // a[32], b[32]
constexpr int STATS_ZERO_FLOATS = 20480;

constexpr size_t ST_OFF   = 32768;                    // float offset of transposed s
constexpr size_t ST_FLOATS= 8ull * 1024 * 4672;       // 38,273,024 floats
constexpr size_t OB_FLOATS= 8192ull * 2048;           // 16,777,216 floats

// ---------------------------------------------------------------------------
// Transpose s [8][4672][1024] -> st [8][1024][4672] (per-patch contiguous)
__global__ __launch_bounds__(256)
void transpose_s(const float* __restrict__ s, float* __restrict__ st) {
    __shared__ float tile[32][33];
    const int bi = blockIdx.z;
    const int p0 = blockIdx.x * 32;   // param tile base (4672 = 146*32)
    const int q0 = blockIdx.y * 32;   // patch tile base (1024 = 32*32)
    const int tx = threadIdx.x;       // 0..31
    const int ty = threadIdx.y;       // 0..7
    const float* sb = s + (size_t)bi * 4672 * 1024;
    float* stb = st + (size_t)bi * 1024 * 4672;
    #pragma unroll
    for (int r = ty; r < 32; r += 8)
        tile[r][tx] = sb[(size_t)(p0 + r) * 1024 + q0 + tx];
    __syncthreads();
    #pragma unroll
    for (int r = ty; r < 32; r += 8)
        stb[(size_t)(q0 + r) * 4672 + p0 + tx] = tile[tx][r];
}

// ---------------------------------------------------------------------------
// One block per patch. STAGE: how deep (1,2,3). STORE_O: store raw stage-3
// conv output to obuf. WRITE_OUT: apply BN3 + residual, write output.
template<int STAGE, int STORE_O, int WRITE_OUT>
__global__ __launch_bounds__(NTHREADS)
void patch_k(const float* __restrict__ x, const float* __restrict__ s,
             const float* __restrict__ st, float* __restrict__ obuf,
             float* __restrict__ ws, float* __restrict__ out) {
    __shared__ float A[5248];      // xs[3200] + w1[2048]; later z[64*65=4160] overlays
    __shared__ float Bsh[6464];    // y[64*101]; later w3T[2112] overlays
    __shared__ float w2s[576];
    __shared__ float fin_s[256];   // a1,b1 (64+64), a2,b2 (64+64)

    const int t    = threadIdx.x;
    const int blk  = blockIdx.x;
    const int bi   = blk >> 10;
    const int f    = (blk >> 5) & 31;
    const int g    = blk & 31;
    const int slot = blk & 63;

    // ---- load patch (reflect halo) into A[0..3199] : xs[c][10][10]
    const float* xb = x + (size_t)bi * Cc * Hh * Hh;
    for (int i = t; i < Cc * KHc * KHc; i += NTHREADS) {
        int c = i / 100;
        int rem = i - c * 100;
        int pr = rem / 10, pc = rem - pr * 10;
        int row = f * PHc - 1 + pr; row = row < 0 ? -row : (row > 255 ? 510 - row : row);
        int col = g * PHc - 1 + pc; col = col < 0 ? -col : (col > 255 ? 510 - col : col);
        A[i] = xb[(size_t)c * 65536 + row * 256 + col];
    }

    // ---- load weights (coalesced from st when available)
    const bool use_st = (st != nullptr);
    const float* wp_st = st + (size_t)(bi * 1024 + f * 32 + g) * 4672;
    const float* wp_s  = s + (size_t)bi * 4672 * 1024 + f * 32 + g;
    if (use_st) {
        const float4* w4 = (const float4*)wp_st;
        float4* a4 = (float4*)(A + 3200);
        for (int i = t; i < 512; i += NTHREADS) a4[i] = w4[i];
        if (STAGE >= 2) {
            const float4* w24 = (const float4*)(wp_st + R1c);
            float4* z4 = (float4*)w2s;
            for (int i = t; i < 144; i += NTHREADS) z4[i] = w24[i];
        }
    } else {
        for (int i = t; i < 2048; i += NTHREADS) A[3200 + i] = wp_s[(size_t)i * 1024];
        if (STAGE >= 2)
            for (int i = t; i < 576; i += NTHREADS) w2s[i] = wp_s[(size_t)(R1c + i) * 1024];
    }
    if (STAGE >= 2) {
        if (t < 128) fin_s[t] = ws[FIN1 + t];
        if (STAGE >= 3 && t < 128) fin_s[128 + t] = ws[FIN2 + t];
    }
    __syncthreads();

    // ---- stage 1: y[64][100] = w1 * xs  (8 ch x up-to-4 pix per thread)
    const int og = t >> 5;      // channel group: channels og*8..og*8+7
    const int pl = t & 31;      // pixel lane: pix = pl, pl+32, pl+64, (pl+96)
    float acc[8][4];
    #pragma unroll
    for (int i = 0; i < 8; i++) { acc[i][0]=0.f; acc[i][1]=0.f; acc[i][2]=0.f; acc[i][3]=0.f; }
    #pragma unroll 4
    for (int c = 0; c < 32; c++) {
        float xa0 = A[c*100 + pl];
        float xa1 = A[c*100 + pl + 32];
        float xa2 = A[c*100 + pl + 64];
        float xa3 = A[c*100 + pl + 96];   // garbage when pl>=4, masked below
        const float* wrow = &A[3200 + og*256 + c];
        #pragma unroll
        for (int i = 0; i < 8; i++) {
            float wv = wrow[i*32];
            acc[i][0] += wv * xa0; acc[i][1] += wv * xa1;
            acc[i][2] += wv * xa2; acc[i][3] += wv * xa3;
        }
    }
    #pragma unroll
    for (int i = 0; i < 8; i++) {
        int ch = og*8 + i;
        Bsh[ch*YS + pl]      = acc[i][0];
        Bsh[ch*YS + pl + 32] = acc[i][1];
        Bsh[ch*YS + pl + 64] = acc[i][2];
        if (pl < 4) Bsh[ch*YS + pl + 96] = acc[i][3];
    }
    if (STAGE == 1) {
        #pragma unroll
        for (int i = 0; i < 8; i++) {
            float a3v = (pl < 4) ? acc[i][3] : 0.f;
            float sm = acc[i][0] + acc[i][1] + acc[i][2] + a3v;
            float qq = acc[i][0]*acc[i][0] + acc[i][1]*acc[i][1] + acc[i][2]*acc[i][2] + a3v*a3v;
            #pragma unroll
            for (int m = 16; m >= 1; m >>= 1) { sm += __shfl_xor(sm, m); qq += __shfl_xor(qq, m); }
            if (pl == 0) {
                atomicAdd(&ws[SLOTS1  + (og*8 + i)*64 + slot], sm);
                atomicAdd(&ws[SLOTS1Q + (og*8 + i)*64 + slot], qq);
            }
        }
        return;
    }

    __syncthreads();
    // ---- BN1 + relu6 in place on y
    for (int idx = t; idx < 6400; idx += NTHREADS) {
        int ch = idx / 100; int p = idx - ch * 100;
        float v = Bsh[ch*YS + p] * fin_s[ch] + fin_s[64 + ch];
        Bsh[ch*YS + p] = fminf(fmaxf(v, 0.f), 6.f);
    }
    // save residual x before z overlays xs
    float xres[2][4];
    if (WRITE_OUT) {
        int og3 = t >> 4, pg = t & 15;
        int p = pg >> 1, q0c = (pg & 1) * 4;
        #pragma unroll
        for (int i = 0; i < 2; i++)
            #pragma unroll
            for (int k = 0; k < 4; k++)
                xres[i][k] = A[(og3*2 + i)*100 + (p+1)*10 + (q0c + k + 1)];
    }
    __syncthreads();

    // ---- stage 2: depthwise 3x3 valid -> z[64][8][8] (stride ZS) into A
    const int ch2 = t >> 2;
    const int quad = t & 3;
    const int p0 = quad * 2;
    float yr[4][10];
    #pragma unroll
    for (int r = 0; r < 4; r++)
        #pragma unroll
        for (int cc = 0; cc < 10; cc++)
            yr[r][cc] = Bsh[ch2*YS + (p0 + r)*10 + cc];
    float zacc[2][8];
    #pragma unroll
    for (int pr = 0; pr < 2; pr++)
        #pragma unroll
        for (int q = 0; q < 8; q++) zacc[pr][q] = 0.f;
    #pragma unroll
    for (int u = 0; u < 3; u++)
        #pragma unroll
        for (int v = 0; v < 3; v++) {
            float wv = w2s[ch2*9 + u*3 + v];
            #pragma unroll
            for (int pr = 0; pr < 2; pr++)
                #pragma unroll
                for (int q = 0; q < 8; q++)
                    zacc[pr][q] += wv * yr[pr + u][q + v];
        }
    float zs = 0.f, zq = 0.f;
    #pragma unroll
    for (int pr = 0; pr < 2; pr++)
        #pragma unroll
        for (int q = 0; q < 8; q++) {
            float v = zacc[pr][q];
            A[ch2*ZS + (p0 + pr)*8 + q] = v;
            if (STAGE == 2) { zs += v; zq += v * v; }
        }
    if (STAGE == 2) {
        zs += __shfl_xor(zs, 1); zs += __shfl_xor(zs, 2);
        zq += __shfl_xor(zq, 1); zq += __shfl_xor(zq, 2);
        if (quad == 0) {
            atomicAdd(&ws[SLOTS2  + ch2*64 + slot], zs);
            atomicAdd(&ws[SLOTS2Q + ch2*64 + slot], zq);
        }
        return;
    }

    __syncthreads();   // z complete
    // ---- BN2 + relu6 in place on z
    for (int idx = t; idx < 4096; idx += NTHREADS) {
        int ch = idx >> 6; int p = idx & 63;
        float v = A[ch*ZS + p] * fin_s[128 + ch] + fin_s[192 + ch];
        A[ch*ZS + p] = fminf(fmaxf(v, 0.f), 6.f);
    }
    // load w3 transposed into Bsh[0..2111]: w3T[ch*33 + oc]
    if (use_st) {
        for (int i = t; i < 2048; i += NTHREADS)
            Bsh[(i & 63)*33 + (i >> 6)] = wp_st[R2c + i];
    } else {
        for (int i = t; i < 2048; i += NTHREADS)
            Bsh[(i & 63)*33 + (i >> 6)] = wp_s[(size_t)(R2c + i) * 1024];
    }
    __syncthreads();

    // ---- stage 3: o[32][64] = w3 * zn  (2 oc x 4 pix per thread)
    const int og3 = t >> 4;   // oc pair og3*2, og3*2+1
    const int pg  = t & 15;   // pix pg*4 .. pg*4+3
    float o3[2][4];
    #pragma unroll
    for (int i = 0; i < 2; i++)
        #pragma unroll
        for (int k = 0; k < 4; k++) o3[i][k] = 0.f;
    #pragma unroll 4
    for (int ch = 0; ch < 64; ch++) {
        float zv0 = A[ch*ZS + pg*4];
        float zv1 = A[ch*ZS + pg*4 + 1];
        float zv2 = A[ch*ZS + pg*4 + 2];
        float zv3 = A[ch*ZS + pg*4 + 3];
        float w0  = Bsh[ch*33 + og3*2];
        float w1v = Bsh[ch*33 + og3*2 + 1];
        o3[0][0] += w0*zv0;  o3[0][1] += w0*zv1;  o3[0][2] += w0*zv2;  o3[0][3] += w0*zv3;
        o3[1][0] += w1v*zv0; o3[1][1] += w1v*zv1; o3[1][2] += w1v*zv2; o3[1][3] += w1v*zv3;
    }

    if (STAGE == 3 && !WRITE_OUT) {
        #pragma unroll
        for (int i = 0; i < 2; i++) {
            float sm = o3[i][0] + o3[i][1] + o3[i][2] + o3[i][3];
            float qq = o3[i][0]*o3[i][0] + o3[i][1]*o3[i][1] + o3[i][2]*o3[i][2] + o3[i][3]*o3[i][3];
            #pragma unroll
            for (int m = 8; m >= 1; m >>= 1) { sm += __shfl_xor(sm, m); qq += __shfl_xor(qq, m); }
            if (pg == 0) {
                atomicAdd(&ws[SLOTS3  + (og3*2 + i)*64 + slot], sm);
                atomicAdd(&ws[SLOTS3Q + (og3*2 + i)*64 + slot], qq);
            }
        }
    }
    if (STORE_O) {
        float* ob = obuf + (size_t)blk * 2048;
        #pragma unroll
        for (int i = 0; i < 2; i++) {
            float4 v4 = make_float4(o3[i][0], o3[i][1], o3[i][2], o3[i][3]);
            *(float4*)(ob + (og3*2 + i)*64 + pg*4) = v4;
        }
    }
    if (WRITE_OUT) {
        #pragma unroll
        for (int i = 0; i < 2; i++) {
            int oc = og3*2 + i;
            float a3 = ws[FIN3 + oc], b3c = ws[FIN3 + 32 + oc];
            int p = pg >> 1, q0c = (pg & 1) * 4;
            size_t oidx = ((size_t)((bi*32 + oc)*256 + f*8 + p))*256 + g*8 + q0c;
            float4 v4 = make_float4(xres[i][0] + o3[i][0]*a3 + b3c,
                                    xres[i][1] + o3[i][1]*a3 + b3c,
                                    xres[i][2] + o3[i][2]*a3 + b3c,
                                    xres[i][3] + o3[i][3]*a3 + b3c);
            *(float4*)(out + oidx) = v4;
        }
    }
}

__global__ void finalize_k(float* __restrict__ ws, int stage,
                           const float* __restrict__ gamma, const float* __restrict__ beta) {
    int ch = threadIdx.x;
    int nch = (stage == 3) ? 32 : 64;
    if (ch >= nch) return;
    int so = (stage == 1) ? SLOTS1  : (stage == 2) ? SLOTS2  : SLOTS3;
    int sq = (stage == 1) ? SLOTS1Q : (stage == 2) ? SLOTS2Q : SLOTS3Q;
    int fo = (stage == 1) ? FIN1    : (stage == 2) ? FIN2    : FIN3;
    float N = (stage == 1) ? 819200.0f : 524288.0f;
    float sm = 0.f, qq = 0.f;
    for (int j = 0; j < 64; j++) { sm += ws[so + ch*64 + j]; qq += ws[sq + ch*64 + j]; }
    float mean = sm / N;
    float var  = qq / N - mean * mean;
    float rstd = rsqrtf(var + EPSc);
    float a = rstd * gamma[ch];
    ws[fo + ch]       = a;
    ws[fo + nch + ch] = beta[ch] - mean * a;
}

__global__ void k4_read(const float* __restrict__ x, const float* __restrict__ ws,
                        const float* __restrict__ obuf, float* __restrict__ out) {
    size_t idx = (size_t)blockIdx.x * NTHREADS + threadIdx.x;
    int wq = idx & 255;
    int h  = (idx >> 8) & 255;
    int oc = (idx >> 16) & 31;
    int bi = idx >> 21;
    float a3 = ws[FIN3 + oc], b3c = ws[FIN3 + 32 + oc];
    int fa = h >> 3, ga = wq >> 3;
    int pix = ((h & 7) << 3) | (wq & 7);
    int blk = (bi << 10) | (fa << 5) | ga;
    float o = obuf[(size_t)blk * 2048 + oc*64 + pix];
    out[idx] = x[idx] + o * a3 + b3c;
}

extern "C" void kernel_launch(void* const* d_in, const int* in_sizes, int n_in,
                              void* d_out, int out_size, void* d_ws, size_t ws_size,
                              hipStream_t stream) {
    const float* x  = (const float*)d_in[0];
    const float* s  = (const float*)d_in[1];
    const float* g1 = (const float*)d_in[2];
    const float* b1 = (const float*)d_in[3];
    const float* g2 = (const float*)d_in[4];
    const float* b2 = (const float*)d_in[5];
    const float* g3 = (const float*)d_in[6];
    const float* b3 = (const float*)d_in[7];
    float* out = (float*)d_out;
    float* ws  = (float*)d_ws;

    hipMemsetAsync(d_ws, 0, STATS_ZERO_FLOATS * sizeof(float), stream);

    const size_t need_full = (ST_OFF + ST_FLOATS + OB_FLOATS) * 4;   // ~220 MB
    const size_t need_st   = (ST_OFF + ST_FLOATS) * 4;               // ~153 MB
    const size_t need_ob   = (32768 + OB_FLOATS) * 4;                // ~67 MB

    float* st = nullptr;
    float* ob = nullptr;
    if (ws_size >= need_full)      { st = ws + ST_OFF; ob = ws + ST_OFF + ST_FLOATS; }
    else if (ws_size >= need_st)   { st = ws + ST_OFF; }
    else if (ws_size >= need_ob)   { ob = ws + 32768; }

    if (st) transpose_s<<<dim3(146, 32, 8), dim3(32, 8), 0, stream>>>(s, st);

    patch_k<1,0,0><<<8192, NTHREADS, 0, stream>>>(x, s, st, ob, ws, out);
    finalize_k<<<1, 64, 0, stream>>>(ws, 1, g1, b1);
    patch_k<2,0,0><<<8192, NTHREADS, 0, stream>>>(x, s, st, ob, ws, out);
    finalize_k<<<1, 64, 0, stream>>>(ws, 2, g2, b2);
    if (ob) {
        patch_k<3,1,0><<<8192, NTHREADS, 0, stream>>>(x, s, st, ob, ws, out);
        finalize_k<<<1, 64, 0, stream>>>(ws, 3, g3, b3);
        k4_read<<<65536, NTHREADS, 0, stream>>>(x, ws, ob, out);
    } else {
        patch_k<3,0,0><<<8192, NTHREADS, 0, stream>>>(x, s, st, ob, ws, out);
        finalize_k<<<1, 64, 0, stream>>>(ws, 3, g3, b3);
        patch_k<3,0,1><<<8192, NTHREADS, 0, stream>>>(x, s, st, ob, ws, out);
    }
}

// Round 3
// 477.226 us; speedup vs baseline: 1.5307x; 1.4092x over previous
//
#include <hip/hip_runtime.h>

#define NTHREADS 256

// problem constants
constexpr int Cc   = 32;
constexpr int Hh   = 256;
constexpr int PHc  = 8;
constexpr int KHc  = 10;
constexpr int R1c  = 2048;
constexpr int R2c  = 2624;
constexpr int R3c  = 4672;
constexpr float EPSc = 1e-5f;

// old-kernel LDS strides
constexpr int YS = 101;
constexpr int ZS = 65;

// ws float offsets (stats)
constexpr int SLOTS1  = 0;
constexpr int SLOTS1Q = 4096;
constexpr int SLOTS2  = 8192;
constexpr int SLOTS2Q = 12288;
constexpr int SLOTS3  = 16384;
constexpr int SLOTS3Q = 18432;
constexpr int FIN1    = 20480;
constexpr int FIN2    = 20608;
constexpr int FIN3    = 20736;
constexpr int STATS_ZERO_FLOATS = 20480;

constexpr size_t ST_OFF    = 32768;                  // float offset of transposed s
constexpr size_t ST_FLOATS = 8ull * 1024 * 4672;     // 38,273,024 floats
constexpr size_t Z_BYTE_OFF = (ST_OFF + ST_FLOATS) * 4;  // 153,223,168
constexpr size_t Z_BYTES    = 8192ull * 4096 * 2;        // 67,108,864 (z bf16)
constexpr size_t OB_FLOATS  = 8192ull * 2048;            // old fp32 o buffer

// ---- bf16 helpers -------------------------------------------------------
__device__ __forceinline__ ushort f_to_bf16(float f) {
    union { float f; unsigned int i; } v; v.f = f;
    unsigned int r = (v.i + 0x7fffu + ((v.i >> 16) & 1u)) >> 16;
    return (ushort)r;
}
__device__ __forceinline__ float bf16lo_to_f(unsigned int u) {
    union { unsigned int i; float f; } v; v.i = u << 16; return v.f;
}
__device__ __forceinline__ float bf16hi_to_f(unsigned int u) {
    union { unsigned int i; float f; } v; v.i = u & 0xffff0000u; return v.f;
}

// ---------------------------------------------------------------------------
// Transpose s [8][4672][1024] -> st [8][1024][4672]
__global__ __launch_bounds__(256)
void transpose_s(const float* __restrict__ s, float* __restrict__ st) {
    __shared__ float tile[32][33];
    const int bi = blockIdx.z;
    const int p0 = blockIdx.x * 32;
    const int q0 = blockIdx.y * 32;
    const int tx = threadIdx.x;
    const int ty = threadIdx.y;
    const float* sb = s + (size_t)bi * 4672 * 1024;
    float* stb = st + (size_t)bi * 1024 * 4672;
    #pragma unroll
    for (int r = ty; r < 32; r += 8)
        tile[r][tx] = sb[(size_t)(p0 + r) * 1024 + q0 + tx];
    __syncthreads();
    #pragma unroll
    for (int r = ty; r < 32; r += 8)
        stb[(size_t)(q0 + r) * 4672 + p0 + tx] = tile[tx][r];
}

// ---------------------------------------------------------------------------
// K1: lean stage-1 stats only. LDS = 21KB -> 7 blocks/CU.
__global__ __launch_bounds__(NTHREADS)
void k1_stats(const float* __restrict__ x, const float* __restrict__ s,
              const float* __restrict__ st, float* __restrict__ ws) {
    __shared__ float A[5248];   // xs[3200] + w1[2048]
    const int t = threadIdx.x, blk = blockIdx.x;
    const int bi = blk >> 10, f = (blk >> 5) & 31, g = blk & 31, slot = blk & 63;

    const float* xb = x + (size_t)bi * Cc * Hh * Hh;
    for (int i = t; i < 3200; i += NTHREADS) {
        int c = i / 100;
        int rem = i - c * 100;
        int pr = rem / 10, pc = rem - pr * 10;
        int row = f * PHc - 1 + pr; row = row < 0 ? -row : (row > 255 ? 510 - row : row);
        int col = g * PHc - 1 + pc; col = col < 0 ? -col : (col > 255 ? 510 - col : col);
        A[i] = xb[(size_t)c * 65536 + row * 256 + col];
    }
    if (st) {
        const float4* w4 = (const float4*)(st + (size_t)(bi * 1024 + f * 32 + g) * 4672);
        float4* a4 = (float4*)(A + 3200);
        for (int i = t; i < 512; i += NTHREADS) a4[i] = w4[i];
    } else {
        const float* wp = s + (size_t)bi * 4672 * 1024 + f * 32 + g;
        for (int i = t; i < 2048; i += NTHREADS) A[3200 + i] = wp[(size_t)i * 1024];
    }
    __syncthreads();

    const int og = t >> 5, pl = t & 31;
    float acc[8][4];
    #pragma unroll
    for (int i = 0; i < 8; i++) { acc[i][0]=0.f; acc[i][1]=0.f; acc[i][2]=0.f; acc[i][3]=0.f; }
    #pragma unroll 4
    for (int c = 0; c < 32; c++) {
        float xa0 = A[c*100 + pl];
        float xa1 = A[c*100 + pl + 32];
        float xa2 = A[c*100 + pl + 64];
        float xa3 = A[c*100 + pl + 96];
        const float* wrow = &A[3200 + og*256 + c];
        #pragma unroll
        for (int i = 0; i < 8; i++) {
            float wv = wrow[i*32];
            acc[i][0] += wv * xa0; acc[i][1] += wv * xa1;
            acc[i][2] += wv * xa2; acc[i][3] += wv * xa3;
        }
    }
    #pragma unroll
    for (int i = 0; i < 8; i++) {
        float a3v = (pl < 4) ? acc[i][3] : 0.f;
        float sm = acc[i][0] + acc[i][1] + acc[i][2] + a3v;
        float qq = acc[i][0]*acc[i][0] + acc[i][1]*acc[i][1] + acc[i][2]*acc[i][2] + a3v*a3v;
        #pragma unroll
        for (int m = 16; m >= 1; m >>= 1) { sm += __shfl_xor(sm, m); qq += __shfl_xor(qq, m); }
        if (pl == 0) {
            atomicAdd(&ws[SLOTS1  + (og*8 + i)*64 + slot], sm);
            atomicAdd(&ws[SLOTS1Q + (og*8 + i)*64 + slot], qq);
        }
    }
}

// ---------------------------------------------------------------------------
// K2: stage1 -> BN1+relu6 in-reg -> y bf16 in LDS (overlaid on xs) -> depthwise
//     -> stats2 + store raw z bf16 to ws. Requires st + zbuf. LDS ~24KB.
__global__ __launch_bounds__(NTHREADS)
void k2_store(const float* __restrict__ x, const float* __restrict__ st,
              ushort* __restrict__ zbuf, float* __restrict__ ws) {
    __shared__ float xy[3840];     // xs fp32; later y bf16 [ch*120 + row*12 + col]
    __shared__ float w1s[2048];    // w1; first 576 later overlaid with w2
    __shared__ float fin_s[128];   // a1[64], b1[64]

    const int t = threadIdx.x, blk = blockIdx.x;
    const int bi = blk >> 10, f = (blk >> 5) & 31, g = blk & 31, slot = blk & 63;

    const float* xb = x + (size_t)bi * Cc * Hh * Hh;
    for (int i = t; i < 3200; i += NTHREADS) {
        int c = i / 100;
        int rem = i - c * 100;
        int pr = rem / 10, pc = rem - pr * 10;
        int row = f * PHc - 1 + pr; row = row < 0 ? -row : (row > 255 ? 510 - row : row);
        int col = g * PHc - 1 + pc; col = col < 0 ? -col : (col > 255 ? 510 - col : col);
        xy[i] = xb[(size_t)c * 65536 + row * 256 + col];
    }
    const float* wp = st + (size_t)(bi * 1024 + f * 32 + g) * 4672;
    {
        const float4* w4 = (const float4*)wp;
        float4* a4 = (float4*)w1s;
        for (int i = t; i < 512; i += NTHREADS) a4[i] = w4[i];
    }
    // w2 staged through registers (w1s is still live)
    float w2r0 = wp[R1c + t];
    float w2r1 = wp[R1c + 256 + t];
    float w2r2 = (t < 64) ? wp[R1c + 512 + t] : 0.f;
    if (t < 128) fin_s[t] = ws[FIN1 + t];
    __syncthreads();

    // stage 1
    const int og = t >> 5, pl = t & 31;
    float acc[8][4];
    #pragma unroll
    for (int i = 0; i < 8; i++) { acc[i][0]=0.f; acc[i][1]=0.f; acc[i][2]=0.f; acc[i][3]=0.f; }
    #pragma unroll 4
    for (int c = 0; c < 32; c++) {
        float xa0 = xy[c*100 + pl];
        float xa1 = xy[c*100 + pl + 32];
        float xa2 = xy[c*100 + pl + 64];
        float xa3 = xy[c*100 + pl + 96];
        const float* wrow = &w1s[og*256 + c];
        #pragma unroll
        for (int i = 0; i < 8; i++) {
            float wv = wrow[i*32];
            acc[i][0] += wv * xa0; acc[i][1] += wv * xa1;
            acc[i][2] += wv * xa2; acc[i][3] += wv * xa3;
        }
    }
    __syncthreads();   // all xs / w1 reads done

    // BN1 + relu6 in-reg, y -> bf16 overlay
    ushort* yb = (ushort*)xy;
    #pragma unroll
    for (int i = 0; i < 8; i++) {
        int ch = og*8 + i;
        float a1 = fin_s[ch], b1 = fin_s[64 + ch];
        #pragma unroll
        for (int k = 0; k < 4; k++) {
            int p = pl + k*32;
            if (k < 3 || pl < 4) {
                float v = fminf(fmaxf(acc[i][k]*a1 + b1, 0.f), 6.f);
                int row = p / 10, col = p - row*10;
                yb[ch*120 + row*12 + col] = f_to_bf16(v);
            }
        }
    }
    // w2 regs -> LDS (over w1)
    w1s[t] = w2r0;
    w1s[256 + t] = w2r1;
    if (t < 64) w1s[512 + t] = w2r2;
    __syncthreads();

    // stage 2: depthwise 3x3
    const int ch2 = t >> 2, quad = t & 3, p0 = quad * 2;
    const unsigned int* yu = (const unsigned int*)xy;
    float yr[4][10];
    #pragma unroll
    for (int r = 0; r < 4; r++) {
        int base = ch2*60 + (p0 + r)*6;   // uint index
        #pragma unroll
        for (int k = 0; k < 5; k++) {
            unsigned int u = yu[base + k];
            yr[r][2*k]   = bf16lo_to_f(u);
            yr[r][2*k+1] = bf16hi_to_f(u);
        }
    }
    float zacc[2][8];
    #pragma unroll
    for (int pr = 0; pr < 2; pr++)
        #pragma unroll
        for (int q = 0; q < 8; q++) zacc[pr][q] = 0.f;
    #pragma unroll
    for (int u = 0; u < 3; u++)
        #pragma unroll
        for (int v = 0; v < 3; v++) {
            float wv = w1s[ch2*9 + u*3 + v];
            #pragma unroll
            for (int pr = 0; pr < 2; pr++)
                #pragma unroll
                for (int q = 0; q < 8; q++)
                    zacc[pr][q] += wv * yr[pr + u][q + v];
        }
    // stats2
    float zs = 0.f, zq = 0.f;
    #pragma unroll
    for (int pr = 0; pr < 2; pr++)
        #pragma unroll
        for (int q = 0; q < 8; q++) { float v = zacc[pr][q]; zs += v; zq += v*v; }
    zs += __shfl_xor(zs, 1); zs += __shfl_xor(zs, 2);
    zq += __shfl_xor(zq, 1); zq += __shfl_xor(zq, 2);
    if (quad == 0) {
        atomicAdd(&ws[SLOTS2  + ch2*64 + slot], zs);
        atomicAdd(&ws[SLOTS2Q + ch2*64 + slot], zq);
    }
    // store raw z bf16 (coalesced)
    ushort* zp = zbuf + (size_t)blk * 4096;
    #pragma unroll
    for (int pr = 0; pr < 2; pr++) {
        uint4 pk;
        pk.x = (unsigned int)f_to_bf16(zacc[pr][0]) | ((unsigned int)f_to_bf16(zacc[pr][1]) << 16);
        pk.y = (unsigned int)f_to_bf16(zacc[pr][2]) | ((unsigned int)f_to_bf16(zacc[pr][3]) << 16);
        pk.z = (unsigned int)f_to_bf16(zacc[pr][4]) | ((unsigned int)f_to_bf16(zacc[pr][5]) << 16);
        pk.w = (unsigned int)f_to_bf16(zacc[pr][6]) | ((unsigned int)f_to_bf16(zacc[pr][7]) << 16);
        *(uint4*)(zp + ch2*64 + (p0 + pr)*8) = pk;
    }
}

// ---------------------------------------------------------------------------
// K3: read z bf16 + w3 (st); BN2+relu6 on load; stage-3 GEMM.
// WRITE_OUT=0: stats3.  WRITE_OUT=1: BN3 + residual + output.
template<int WRITE_OUT>
__global__ __launch_bounds__(NTHREADS)
void k3_k(const float* __restrict__ x, const ushort* __restrict__ zbuf,
          const float* __restrict__ st, float* __restrict__ ws,
          float* __restrict__ out) {
    __shared__ float zh_f[2048];   // zhat bf16 [ch*64 + pix] (as ushort[4096])
    __shared__ float w3T[2112];    // [ch*33 + oc]

    const int t = threadIdx.x, blk = blockIdx.x;
    const int bi = blk >> 10, f = (blk >> 5) & 31, g = blk & 31, slot = blk & 63;

    // load z, apply BN2+relu6, store zhat bf16 in LDS
    const uint4* zsrc = (const uint4*)(zbuf + (size_t)blk * 4096);
    uint4* zdst = (uint4*)zh_f;
    for (int i = t; i < 512; i += NTHREADS) {
        uint4 v = zsrc[i];
        int ch = i >> 3;
        float a2 = ws[FIN2 + ch], b2 = ws[FIN2 + 64 + ch];
        unsigned int w[4] = {v.x, v.y, v.z, v.w};
        #pragma unroll
        for (int k = 0; k < 4; k++) {
            float lo = fminf(fmaxf(bf16lo_to_f(w[k])*a2 + b2, 0.f), 6.f);
            float hi = fminf(fmaxf(bf16hi_to_f(w[k])*a2 + b2, 0.f), 6.f);
            w[k] = (unsigned int)f_to_bf16(lo) | ((unsigned int)f_to_bf16(hi) << 16);
        }
        zdst[i] = make_uint4(w[0], w[1], w[2], w[3]);
    }
    const float* wp = st + (size_t)(bi * 1024 + f * 32 + g) * 4672;
    for (int i = t; i < 2048; i += NTHREADS)
        w3T[(i & 63)*33 + (i >> 6)] = wp[R2c + i];
    __syncthreads();

    // stage 3: 2 oc x 4 pix per thread
    const int og3 = t >> 4, pg = t & 15;
    const ushort* zhu = (const ushort*)zh_f;
    float o3[2][4];
    #pragma unroll
    for (int i = 0; i < 2; i++)
        #pragma unroll
        for (int k = 0; k < 4; k++) o3[i][k] = 0.f;
    #pragma unroll 4
    for (int ch = 0; ch < 64; ch++) {
        uint2 zz = *(const uint2*)(zhu + ch*64 + pg*4);
        float z0 = bf16lo_to_f(zz.x), z1 = bf16hi_to_f(zz.x);
        float z2 = bf16lo_to_f(zz.y), z3 = bf16hi_to_f(zz.y);
        float w0  = w3T[ch*33 + og3*2];
        float w1v = w3T[ch*33 + og3*2 + 1];
        o3[0][0] += w0*z0;  o3[0][1] += w0*z1;  o3[0][2] += w0*z2;  o3[0][3] += w0*z3;
        o3[1][0] += w1v*z0; o3[1][1] += w1v*z1; o3[1][2] += w1v*z2; o3[1][3] += w1v*z3;
    }

    if (!WRITE_OUT) {
        #pragma unroll
        for (int i = 0; i < 2; i++) {
            float sm = o3[i][0] + o3[i][1] + o3[i][2] + o3[i][3];
            float qq = o3[i][0]*o3[i][0] + o3[i][1]*o3[i][1] + o3[i][2]*o3[i][2] + o3[i][3]*o3[i][3];
            #pragma unroll
            for (int m = 8; m >= 1; m >>= 1) { sm += __shfl_xor(sm, m); qq += __shfl_xor(qq, m); }
            if (pg == 0) {
                atomicAdd(&ws[SLOTS3  + (og3*2 + i)*64 + slot], sm);
                atomicAdd(&ws[SLOTS3Q + (og3*2 + i)*64 + slot], qq);
            }
        }
    } else {
        #pragma unroll
        for (int i = 0; i < 2; i++) {
            int oc = og3*2 + i;
            float a3 = ws[FIN3 + oc], b3c = ws[FIN3 + 32 + oc];
            int p = pg >> 1, q0c = (pg & 1) * 4;
            size_t oidx = ((size_t)((bi*32 + oc)*256 + f*8 + p))*256 + g*8 + q0c;
            float4 xv = *(const float4*)(x + oidx);
            float4 v4 = make_float4(xv.x + o3[i][0]*a3 + b3c,
                                    xv.y + o3[i][1]*a3 + b3c,
                                    xv.z + o3[i][2]*a3 + b3c,
                                    xv.w + o3[i][3]*a3 + b3c);
            *(float4*)(out + oidx) = v4;
        }
    }
}

// ---------------------------------------------------------------------------
// OLD fallback kernels (round-2, unchanged behavior)
template<int STAGE, int STORE_O, int WRITE_OUT>
__global__ __launch_bounds__(NTHREADS)
void patch_k(const float* __restrict__ x, const float* __restrict__ s,
             const float* __restrict__ st, float* __restrict__ obuf,
             float* __restrict__ ws, float* __restrict__ out) {
    __shared__ float A[5248];
    __shared__ float Bsh[6464];
    __shared__ float w2s[576];
    __shared__ float fin_s[256];

    const int t = threadIdx.x, blk = blockIdx.x;
    const int bi = blk >> 10, f = (blk >> 5) & 31, g = blk & 31, slot = blk & 63;

    const float* xb = x + (size_t)bi * Cc * Hh * Hh;
    for (int i = t; i < 3200; i += NTHREADS) {
        int c = i / 100;
        int rem = i - c * 100;
        int pr = rem / 10, pc = rem - pr * 10;
        int row = f * PHc - 1 + pr; row = row < 0 ? -row : (row > 255 ? 510 - row : row);
        int col = g * PHc - 1 + pc; col = col < 0 ? -col : (col > 255 ? 510 - col : col);
        A[i] = xb[(size_t)c * 65536 + row * 256 + col];
    }
    const bool use_st = (st != nullptr);
    const float* wp_st = st + (size_t)(bi * 1024 + f * 32 + g) * 4672;
    const float* wp_s  = s + (size_t)bi * 4672 * 1024 + f * 32 + g;
    if (use_st) {
        const float4* w4 = (const float4*)wp_st;
        float4* a4 = (float4*)(A + 3200);
        for (int i = t; i < 512; i += NTHREADS) a4[i] = w4[i];
        if (STAGE >= 2) {
            const float4* w24 = (const float4*)(wp_st + R1c);
            float4* z4 = (float4*)w2s;
            for (int i = t; i < 144; i += NTHREADS) z4[i] = w24[i];
        }
    } else {
        for (int i = t; i < 2048; i += NTHREADS) A[3200 + i] = wp_s[(size_t)i * 1024];
        if (STAGE >= 2)
            for (int i = t; i < 576; i += NTHREADS) w2s[i] = wp_s[(size_t)(R1c + i) * 1024];
    }
    if (STAGE >= 2) {
        if (t < 128) fin_s[t] = ws[FIN1 + t];
        if (STAGE >= 3 && t < 128) fin_s[128 + t] = ws[FIN2 + t];
    }
    __syncthreads();

    const int og = t >> 5, pl = t & 31;
    float acc[8][4];
    #pragma unroll
    for (int i = 0; i < 8; i++) { acc[i][0]=0.f; acc[i][1]=0.f; acc[i][2]=0.f; acc[i][3]=0.f; }
    #pragma unroll 4
    for (int c = 0; c < 32; c++) {
        float xa0 = A[c*100 + pl];
        float xa1 = A[c*100 + pl + 32];
        float xa2 = A[c*100 + pl + 64];
        float xa3 = A[c*100 + pl + 96];
        const float* wrow = &A[3200 + og*256 + c];
        #pragma unroll
        for (int i = 0; i < 8; i++) {
            float wv = wrow[i*32];
            acc[i][0] += wv * xa0; acc[i][1] += wv * xa1;
            acc[i][2] += wv * xa2; acc[i][3] += wv * xa3;
        }
    }
    #pragma unroll
    for (int i = 0; i < 8; i++) {
        int ch = og*8 + i;
        Bsh[ch*YS + pl]      = acc[i][0];
        Bsh[ch*YS + pl + 32] = acc[i][1];
        Bsh[ch*YS + pl + 64] = acc[i][2];
        if (pl < 4) Bsh[ch*YS + pl + 96] = acc[i][3];
    }
    if (STAGE == 1) {
        #pragma unroll
        for (int i = 0; i < 8; i++) {
            float a3v = (pl < 4) ? acc[i][3] : 0.f;
            float sm = acc[i][0] + acc[i][1] + acc[i][2] + a3v;
            float qq = acc[i][0]*acc[i][0] + acc[i][1]*acc[i][1] + acc[i][2]*acc[i][2] + a3v*a3v;
            #pragma unroll
            for (int m = 16; m >= 1; m >>= 1) { sm += __shfl_xor(sm, m); qq += __shfl_xor(qq, m); }
            if (pl == 0) {
                atomicAdd(&ws[SLOTS1  + (og*8 + i)*64 + slot], sm);
                atomicAdd(&ws[SLOTS1Q + (og*8 + i)*64 + slot], qq);
            }
        }
        return;
    }

    __syncthreads();
    for (int idx = t; idx < 6400; idx += NTHREADS) {
        int ch = idx / 100; int p = idx - ch * 100;
        float v = Bsh[ch*YS + p] * fin_s[ch] + fin_s[64 + ch];
        Bsh[ch*YS + p] = fminf(fmaxf(v, 0.f), 6.f);
    }
    float xres[2][4];
    if (WRITE_OUT) {
        int og3 = t >> 4, pg = t & 15;
        int p = pg >> 1, q0c = (pg & 1) * 4;
        #pragma unroll
        for (int i = 0; i < 2; i++)
            #pragma unroll
            for (int k = 0; k < 4; k++)
                xres[i][k] = A[(og3*2 + i)*100 + (p+1)*10 + (q0c + k + 1)];
    }
    __syncthreads();

    const int ch2 = t >> 2, quad = t & 3, p0 = quad * 2;
    float yr[4][10];
    #pragma unroll
    for (int r = 0; r < 4; r++)
        #pragma unroll
        for (int cc = 0; cc < 10; cc++)
            yr[r][cc] = Bsh[ch2*YS + (p0 + r)*10 + cc];
    float zacc[2][8];
    #pragma unroll
    for (int pr = 0; pr < 2; pr++)
        #pragma unroll
        for (int q = 0; q < 8; q++) zacc[pr][q] = 0.f;
    #pragma unroll
    for (int u = 0; u < 3; u++)
        #pragma unroll
        for (int v = 0; v < 3; v++) {
            float wv = w2s[ch2*9 + u*3 + v];
            #pragma unroll
            for (int pr = 0; pr < 2; pr++)
                #pragma unroll
                for (int q = 0; q < 8; q++)
                    zacc[pr][q] += wv * yr[pr + u][q + v];
        }
    float zs = 0.f, zq = 0.f;
    #pragma unroll
    for (int pr = 0; pr < 2; pr++)
        #pragma unroll
        for (int q = 0; q < 8; q++) {
            float v = zacc[pr][q];
            A[ch2*ZS + (p0 + pr)*8 + q] = v;
            if (STAGE == 2) { zs += v; zq += v * v; }
        }
    if (STAGE == 2) {
        zs += __shfl_xor(zs, 1); zs += __shfl_xor(zs, 2);
        zq += __shfl_xor(zq, 1); zq += __shfl_xor(zq, 2);
        if (quad == 0) {
            atomicAdd(&ws[SLOTS2  + ch2*64 + slot], zs);
            atomicAdd(&ws[SLOTS2Q + ch2*64 + slot], zq);
        }
        return;
    }

    __syncthreads();
    for (int idx = t; idx < 4096; idx += NTHREADS) {
        int ch = idx >> 6; int p = idx & 63;
        float v = A[ch*ZS + p] * fin_s[128 + ch] + fin_s[192 + ch];
        A[ch*ZS + p] = fminf(fmaxf(v, 0.f), 6.f);
    }
    if (use_st) {
        for (int i = t; i < 2048; i += NTHREADS)
            Bsh[(i & 63)*33 + (i >> 6)] = wp_st[R2c + i];
    } else {
        for (int i = t; i < 2048; i += NTHREADS)
            Bsh[(i & 63)*33 + (i >> 6)] = wp_s[(size_t)(R2c + i) * 1024];
    }
    __syncthreads();

    const int og3 = t >> 4, pg = t & 15;
    float o3[2][4];
    #pragma unroll
    for (int i = 0; i < 2; i++)
        #pragma unroll
        for (int k = 0; k < 4; k++) o3[i][k] = 0.f;
    #pragma unroll 4
    for (int ch = 0; ch < 64; ch++) {
        float zv0 = A[ch*ZS + pg*4];
        float zv1 = A[ch*ZS + pg*4 + 1];
        float zv2 = A[ch*ZS + pg*4 + 2];
        float zv3 = A[ch*ZS + pg*4 + 3];
        float w0  = Bsh[ch*33 + og3*2];
        float w1v = Bsh[ch*33 + og3*2 + 1];
        o3[0][0] += w0*zv0;  o3[0][1] += w0*zv1;  o3[0][2] += w0*zv2;  o3[0][3] += w0*zv3;
        o3[1][0] += w1v*zv0; o3[1][1] += w1v*zv1; o3[1][2] += w1v*zv2; o3[1][3] += w1v*zv3;
    }
    if (STAGE == 3 && !WRITE_OUT) {
        #pragma unroll
        for (int i = 0; i < 2; i++) {
            float sm = o3[i][0] + o3[i][1] + o3[i][2] + o3[i][3];
            float qq = o3[i][0]*o3[i][0] + o3[i][1]*o3[i][1] + o3[i][2]*o3[i][2] + o3[i][3]*o3[i][3];
            #pragma unroll
            for (int m = 8; m >= 1; m >>= 1) { sm += __shfl_xor(sm, m); qq += __shfl_xor(qq, m); }
            if (pg == 0) {
                atomicAdd(&ws[SLOTS3  + (og3*2 + i)*64 + slot], sm);
                atomicAdd(&ws[SLOTS3Q + (og3*2 + i)*64 + slot], qq);
            }
        }
    }
    if (STORE_O) {
        float* ob = obuf + (size_t)blk * 2048;
        #pragma unroll
        for (int i = 0; i < 2; i++) {
            float4 v4 = make_float4(o3[i][0], o3[i][1], o3[i][2], o3[i][3]);
            *(float4*)(ob + (og3*2 + i)*64 + pg*4) = v4;
        }
    }
    if (WRITE_OUT) {
        #pragma unroll
        for (int i = 0; i < 2; i++) {
            int oc = og3*2 + i;
            float a3 = ws[FIN3 + oc], b3c = ws[FIN3 + 32 + oc];
            int p = pg >> 1, q0c = (pg & 1) * 4;
            size_t oidx = ((size_t)((bi*32 + oc)*256 + f*8 + p))*256 + g*8 + q0c;
            float4 v4 = make_float4(xres[i][0] + o3[i][0]*a3 + b3c,
                                    xres[i][1] + o3[i][1]*a3 + b3c,
                                    xres[i][2] + o3[i][2]*a3 + b3c,
                                    xres[i][3] + o3[i][3]*a3 + b3c);
            *(float4*)(out + oidx) = v4;
        }
    }
}

__global__ void finalize_k(float* __restrict__ ws, int stage,
                           const float* __restrict__ gamma, const float* __restrict__ beta) {
    int ch = threadIdx.x;
    int nch = (stage == 3) ? 32 : 64;
    if (ch >= nch) return;
    int so = (stage == 1) ? SLOTS1  : (stage == 2) ? SLOTS2  : SLOTS3;
    int sq = (stage == 1) ? SLOTS1Q : (stage == 2) ? SLOTS2Q : SLOTS3Q;
    int fo = (stage == 1) ? FIN1    : (stage == 2) ? FIN2    : FIN3;
    float N = (stage == 1) ? 819200.0f : 524288.0f;
    float sm = 0.f, qq = 0.f;
    for (int j = 0; j < 64; j++) { sm += ws[so + ch*64 + j]; qq += ws[sq + ch*64 + j]; }
    float mean = sm / N;
    float var  = qq / N - mean * mean;
    float rstd = rsqrtf(var + EPSc);
    float a = rstd * gamma[ch];
    ws[fo + ch]       = a;
    ws[fo + nch + ch] = beta[ch] - mean * a;
}

__global__ void k4_read(const float* __restrict__ x, const float* __restrict__ ws,
                        const float* __restrict__ obuf, float* __restrict__ out) {
    size_t idx = (size_t)blockIdx.x * NTHREADS + threadIdx.x;
    int wq = idx & 255;
    int h  = (idx >> 8) & 255;
    int oc = (idx >> 16) & 31;
    int bi = idx >> 21;
    float a3 = ws[FIN3 + oc], b3c = ws[FIN3 + 32 + oc];
    int fa = h >> 3, ga = wq >> 3;
    int pix = ((h & 7) << 3) | (wq & 7);
    int blk = (bi << 10) | (fa << 5) | ga;
    float o = obuf[(size_t)blk * 2048 + oc*64 + pix];
    out[idx] = x[idx] + o * a3 + b3c;
}

// ---------------------------------------------------------------------------
extern "C" void kernel_launch(void* const* d_in, const int* in_sizes, int n_in,
                              void* d_out, int out_size, void* d_ws, size_t ws_size,
                              hipStream_t stream) {
    const float* x  = (const float*)d_in[0];
    const float* s  = (const float*)d_in[1];
    const float* g1 = (const float*)d_in[2];
    const float* b1 = (const float*)d_in[3];
    const float* g2 = (const float*)d_in[4];
    const float* b2 = (const float*)d_in[5];
    const float* g3 = (const float*)d_in[6];
    const float* b3 = (const float*)d_in[7];
    float* out = (float*)d_out;
    float* ws  = (float*)d_ws;

    hipMemsetAsync(d_ws, 0, STATS_ZERO_FLOATS * sizeof(float), stream);

    const size_t need_new = Z_BYTE_OFF + Z_BYTES;               // ~220.3 MB
    const size_t need_st  = (ST_OFF + ST_FLOATS) * 4;           // ~153 MB
    const size_t need_ob  = (32768 + OB_FLOATS) * 4;            // ~67 MB

    if (ws_size >= need_new) {
        // fast path: st + z(bf16)
        float*  st   = ws + ST_OFF;
        ushort* zbuf = (ushort*)((char*)d_ws + Z_BYTE_OFF);
        transpose_s<<<dim3(146, 32, 8), dim3(32, 8), 0, stream>>>(s, st);
        k1_stats<<<8192, NTHREADS, 0, stream>>>(x, s, st, ws);
        finalize_k<<<1, 64, 0, stream>>>(ws, 1, g1, b1);
        k2_store<<<8192, NTHREADS, 0, stream>>>(x, st, zbuf, ws);
        finalize_k<<<1, 64, 0, stream>>>(ws, 2, g2, b2);
        k3_k<0><<<8192, NTHREADS, 0, stream>>>(x, zbuf, st, ws, out);
        finalize_k<<<1, 64, 0, stream>>>(ws, 3, g3, b3);
        k3_k<1><<<8192, NTHREADS, 0, stream>>>(x, zbuf, st, ws, out);
        return;
    }

    // fallback tiers (round-2 behavior)
    float* st = nullptr;
    float* ob = nullptr;
    if (ws_size >= need_st)      { st = ws + ST_OFF; }
    else if (ws_size >= need_ob) { ob = ws + 32768; }

    if (st) transpose_s<<<dim3(146, 32, 8), dim3(32, 8), 0, stream>>>(s, st);

    k1_stats<<<8192, NTHREADS, 0, stream>>>(x, s, st, ws);
    finalize_k<<<1, 64, 0, stream>>>(ws, 1, g1, b1);
    patch_k<2,0,0><<<8192, NTHREADS, 0, stream>>>(x, s, st, ob, ws, out);
    finalize_k<<<1, 64, 0, stream>>>(ws, 2, g2, b2);
    if (ob) {
        patch_k<3,1,0><<<8192, NTHREADS, 0, stream>>>(x, s, st, ob, ws, out);
        finalize_k<<<1, 64, 0, stream>>>(ws, 3, g3, b3);
        k4_read<<<65536, NTHREADS, 0, stream>>>(x, ws, ob, out);
    } else {
        patch_k<3,0,0><<<8192, NTHREADS, 0, stream>>>(x, s, st, ob, ws, out);
        finalize_k<<<1, 64, 0, stream>>>(ws, 3, g3, b3);
        patch_k<3,0,1><<<8192, NTHREADS, 0, stream>>>(x, s, st, ob, ws, out);
    }
}

// Round 4
// 371.220 us; speedup vs baseline: 1.9678x; 1.2856x over previous
//
#include <hip/hip_runtime.h>

#define NTHREADS 256

// problem constants
constexpr int Cc   = 32;
constexpr int Hh   = 256;
constexpr int PHc  = 8;
constexpr int KHc  = 10;
constexpr int R1c  = 2048;
constexpr int R2c  = 2624;
constexpr int R3c  = 4672;
constexpr float EPSc = 1e-5f;

// old-kernel LDS strides
constexpr int YS = 101;
constexpr int ZS = 65;

// ws float offsets (stats)
constexpr int SLOTS1  = 0;
constexpr int SLOTS1Q = 4096;
constexpr int SLOTS2  = 8192;
constexpr int SLOTS2Q = 12288;
constexpr int SLOTS3  = 16384;
constexpr int SLOTS3Q = 18432;
constexpr int FIN1    = 20480;
constexpr int FIN2    = 20608;
constexpr int FIN3    = 20736;
constexpr int STATS_ZERO_FLOATS = 20480;

// ---- NEW fast-path layout (all byte offsets) ----
constexpr size_t ST2_BYTE_OFF = 131072;                       // bf16 transposed s
constexpr size_t ST2_BYTES    = 8ull * 1024 * 4672 * 2;       // 76,546,048
constexpr size_t Y_BYTE_OFF   = ST2_BYTE_OFF + ST2_BYTES;     // 76,677,120
constexpr size_t Y_BYTES      = 8192ull * 6400 * 2;           // 104,857,600
constexpr size_t Z2_BYTE_OFF  = Y_BYTE_OFF + Y_BYTES;         // 181,534,720
constexpr size_t Z2_BYTES     = 8192ull * 4096 * 2;           // 67,108,864
constexpr size_t O_BYTE_OFF   = Y_BYTE_OFF;                   // o overlays dead y
constexpr size_t NEED_NEW2    = Z2_BYTE_OFF + Z2_BYTES;       // 248,643,584

// ---- OLD fallback layout ----
constexpr size_t ST_OFF    = 32768;
constexpr size_t ST_FLOATS = 8ull * 1024 * 4672;
constexpr size_t Z_BYTE_OFF = (ST_OFF + ST_FLOATS) * 4;
constexpr size_t Z_BYTES    = 8192ull * 4096 * 2;
constexpr size_t OB_FLOATS  = 8192ull * 2048;

// ---- bf16 helpers -------------------------------------------------------
__device__ __forceinline__ ushort f_to_bf16(float f) {
    union { float f; unsigned int i; } v; v.f = f;
    unsigned int r = (v.i + 0x7fffu + ((v.i >> 16) & 1u)) >> 16;
    return (ushort)r;
}
__device__ __forceinline__ float bf16lo_to_f(unsigned int u) {
    union { unsigned int i; float f; } v; v.i = u << 16; return v.f;
}
__device__ __forceinline__ float bf16hi_to_f(unsigned int u) {
    union { unsigned int i; float f; } v; v.i = u & 0xffff0000u; return v.f;
}
__device__ __forceinline__ unsigned int pack_bf16(float lo, float hi) {
    return (unsigned int)f_to_bf16(lo) | ((unsigned int)f_to_bf16(hi) << 16);
}

// ---------------------------------------------------------------------------
// Transpose s [8][4672][1024] fp32 -> st bf16 [8][1024][4672]
__global__ __launch_bounds__(256)
void transpose_s_bf16(const float* __restrict__ s, ushort* __restrict__ st) {
    __shared__ float tile[32][33];
    const int bi = blockIdx.z;
    const int p0 = blockIdx.x * 32;
    const int q0 = blockIdx.y * 32;
    const int tx = threadIdx.x, ty = threadIdx.y;
    const float* sb = s + (size_t)bi * 4672 * 1024;
    ushort* stb = st + (size_t)bi * 1024 * 4672;
    #pragma unroll
    for (int r = ty; r < 32; r += 8)
        tile[r][tx] = sb[(size_t)(p0 + r) * 1024 + q0 + tx];
    __syncthreads();
    #pragma unroll
    for (int r = ty; r < 32; r += 8)
        stb[(size_t)(q0 + r) * 4672 + p0 + tx] = f_to_bf16(tile[tx][r]);
}

// ---------------------------------------------------------------------------
// K1: stage-1 conv, stats1, store raw y bf16 [patch][64][100].
__global__ __launch_bounds__(NTHREADS)
void k1_store(const float* __restrict__ x, const ushort* __restrict__ st,
              ushort* __restrict__ ybuf, float* __restrict__ ws) {
    __shared__ float A[5248];   // xs[3200] + w1 fp32 [2048]
    const int t = threadIdx.x, blk = blockIdx.x;
    const int bi = blk >> 10, f = (blk >> 5) & 31, g = blk & 31, slot = blk & 63;

    const float* xb = x + (size_t)bi * Cc * Hh * Hh;
    for (int i = t; i < 3200; i += NTHREADS) {
        int c = i / 100;
        int rem = i - c * 100;
        int pr = rem / 10, pc = rem - pr * 10;
        int row = f * PHc - 1 + pr; row = row < 0 ? -row : (row > 255 ? 510 - row : row);
        int col = g * PHc - 1 + pc; col = col < 0 ? -col : (col > 255 ? 510 - col : col);
        A[i] = xb[(size_t)c * 65536 + row * 256 + col];
    }
    // w1 bf16 -> fp32 LDS (256 uint4 = 2048 bf16, one per thread)
    {
        const uint4* w4 = (const uint4*)(st + (size_t)(bi * 1024 + f * 32 + g) * 4672);
        uint4 v = w4[t];
        unsigned int uu[4] = {v.x, v.y, v.z, v.w};
        #pragma unroll
        for (int k = 0; k < 4; k++) {
            A[3200 + t*8 + 2*k]     = bf16lo_to_f(uu[k]);
            A[3200 + t*8 + 2*k + 1] = bf16hi_to_f(uu[k]);
        }
    }
    __syncthreads();

    const int og = t >> 5, pl = t & 31;
    float acc[8][4];
    #pragma unroll
    for (int i = 0; i < 8; i++) { acc[i][0]=0.f; acc[i][1]=0.f; acc[i][2]=0.f; acc[i][3]=0.f; }
    #pragma unroll 4
    for (int c = 0; c < 32; c++) {
        float xa0 = A[c*100 + pl];
        float xa1 = A[c*100 + pl + 32];
        float xa2 = A[c*100 + pl + 64];
        float xa3 = A[c*100 + pl + 96];
        const float* wrow = &A[3200 + og*256 + c];
        #pragma unroll
        for (int i = 0; i < 8; i++) {
            float wv = wrow[i*32];
            acc[i][0] += wv * xa0; acc[i][1] += wv * xa1;
            acc[i][2] += wv * xa2; acc[i][3] += wv * xa3;
        }
    }
    // store y bf16 + stats1
    ushort* yp = ybuf + (size_t)blk * 6400;
    #pragma unroll
    for (int i = 0; i < 8; i++) {
        int ch = og*8 + i;
        yp[ch*100 + pl]      = f_to_bf16(acc[i][0]);
        yp[ch*100 + pl + 32] = f_to_bf16(acc[i][1]);
        yp[ch*100 + pl + 64] = f_to_bf16(acc[i][2]);
        if (pl < 4) yp[ch*100 + pl + 96] = f_to_bf16(acc[i][3]);

        float a3v = (pl < 4) ? acc[i][3] : 0.f;
        float sm = acc[i][0] + acc[i][1] + acc[i][2] + a3v;
        float qq = acc[i][0]*acc[i][0] + acc[i][1]*acc[i][1] + acc[i][2]*acc[i][2] + a3v*a3v;
        #pragma unroll
        for (int m = 16; m >= 1; m >>= 1) { sm += __shfl_xor(sm, m); qq += __shfl_xor(qq, m); }
        if (pl == 0) {
            atomicAdd(&ws[SLOTS1  + ch*64 + slot], sm);
            atomicAdd(&ws[SLOTS1Q + ch*64 + slot], qq);
        }
    }
}

// ---------------------------------------------------------------------------
// K2: read y bf16, apply BN1+relu6, depthwise 3x3, stats2, store z bf16.
__global__ __launch_bounds__(NTHREADS)
void k2_bn1dw(const ushort* __restrict__ ybuf, const ushort* __restrict__ st,
              ushort* __restrict__ zbuf, float* __restrict__ ws) {
    __shared__ unsigned int yh[3200];   // y-hat bf16 pairs, [ch][100] layout
    __shared__ float w2s[576];
    __shared__ float fin_s[128];

    const int t = threadIdx.x, blk = blockIdx.x;
    const int bi = blk >> 10, f = (blk >> 5) & 31, g = blk & 31, slot = blk & 63;

    if (t < 128) fin_s[t] = ws[FIN1 + t];
    // w2 bf16 -> fp32 LDS
    {
        const unsigned int* w2u = (const unsigned int*)(st + (size_t)(bi * 1024 + f * 32 + g) * 4672 + R1c);
        for (int i = t; i < 288; i += NTHREADS) {
            unsigned int u = w2u[i];
            w2s[2*i]   = bf16lo_to_f(u);
            w2s[2*i+1] = bf16hi_to_f(u);
        }
    }
    __syncthreads();

    // y load + BN1 + relu6 -> LDS (uint2 = 4 elems, never crosses channel)
    {
        const uint2* ysrc = (const uint2*)(ybuf + (size_t)blk * 6400);
        for (int i = t; i < 1600; i += NTHREADS) {
            uint2 v = ysrc[i];
            int ch = i / 25;
            float a1 = fin_s[ch], b1 = fin_s[64 + ch];
            float e0 = fminf(fmaxf(bf16lo_to_f(v.x)*a1 + b1, 0.f), 6.f);
            float e1 = fminf(fmaxf(bf16hi_to_f(v.x)*a1 + b1, 0.f), 6.f);
            float e2 = fminf(fmaxf(bf16lo_to_f(v.y)*a1 + b1, 0.f), 6.f);
            float e3 = fminf(fmaxf(bf16hi_to_f(v.y)*a1 + b1, 0.f), 6.f);
            yh[2*i]   = pack_bf16(e0, e1);
            yh[2*i+1] = pack_bf16(e2, e3);
        }
    }
    __syncthreads();

    // depthwise 3x3
    const int ch2 = t >> 2, quad = t & 3, p0 = quad * 2;
    float yr[4][10];
    #pragma unroll
    for (int r = 0; r < 4; r++) {
        int base = ch2*50 + (p0 + r)*5;
        #pragma unroll
        for (int k = 0; k < 5; k++) {
            unsigned int u = yh[base + k];
            yr[r][2*k]   = bf16lo_to_f(u);
            yr[r][2*k+1] = bf16hi_to_f(u);
        }
    }
    float zacc[2][8];
    #pragma unroll
    for (int pr = 0; pr < 2; pr++)
        #pragma unroll
        for (int q = 0; q < 8; q++) zacc[pr][q] = 0.f;
    #pragma unroll
    for (int u = 0; u < 3; u++)
        #pragma unroll
        for (int v = 0; v < 3; v++) {
            float wv = w2s[ch2*9 + u*3 + v];
            #pragma unroll
            for (int pr = 0; pr < 2; pr++)
                #pragma unroll
                for (int q = 0; q < 8; q++)
                    zacc[pr][q] += wv * yr[pr + u][q + v];
        }
    // stats2
    float zs = 0.f, zq = 0.f;
    #pragma unroll
    for (int pr = 0; pr < 2; pr++)
        #pragma unroll
        for (int q = 0; q < 8; q++) { float v = zacc[pr][q]; zs += v; zq += v*v; }
    zs += __shfl_xor(zs, 1); zs += __shfl_xor(zs, 2);
    zq += __shfl_xor(zq, 1); zq += __shfl_xor(zq, 2);
    if (quad == 0) {
        atomicAdd(&ws[SLOTS2  + ch2*64 + slot], zs);
        atomicAdd(&ws[SLOTS2Q + ch2*64 + slot], zq);
    }
    // store raw z bf16
    ushort* zp = zbuf + (size_t)blk * 4096;
    #pragma unroll
    for (int pr = 0; pr < 2; pr++) {
        uint4 pk;
        pk.x = pack_bf16(zacc[pr][0], zacc[pr][1]);
        pk.y = pack_bf16(zacc[pr][2], zacc[pr][3]);
        pk.z = pack_bf16(zacc[pr][4], zacc[pr][5]);
        pk.w = pack_bf16(zacc[pr][6], zacc[pr][7]);
        *(uint4*)(zp + ch2*64 + (p0 + pr)*8) = pk;
    }
}

// ---------------------------------------------------------------------------
// K3: read z bf16 + w3 bf16; BN2+relu6 on load; stage-3 GEMM; stats3; store o bf16.
__global__ __launch_bounds__(NTHREADS)
void k3_stats_store(const ushort* __restrict__ zbuf, const ushort* __restrict__ st,
                    ushort* __restrict__ obuf, float* __restrict__ ws) {
    __shared__ float zh_f[2048];   // zhat bf16 [ch*64 + pix] (as ushort[4096])
    __shared__ float w3T[2112];    // [ch*33 + oc]

    const int t = threadIdx.x, blk = blockIdx.x;
    const int bi = blk >> 10, f = (blk >> 5) & 31, g = blk & 31, slot = blk & 63;

    const uint4* zsrc = (const uint4*)(zbuf + (size_t)blk * 4096);
    uint4* zdst = (uint4*)zh_f;
    for (int i = t; i < 512; i += NTHREADS) {
        uint4 v = zsrc[i];
        int ch = i >> 3;
        float a2 = ws[FIN2 + ch], b2 = ws[FIN2 + 64 + ch];
        unsigned int w[4] = {v.x, v.y, v.z, v.w};
        #pragma unroll
        for (int k = 0; k < 4; k++) {
            float lo = fminf(fmaxf(bf16lo_to_f(w[k])*a2 + b2, 0.f), 6.f);
            float hi = fminf(fmaxf(bf16hi_to_f(w[k])*a2 + b2, 0.f), 6.f);
            w[k] = pack_bf16(lo, hi);
        }
        zdst[i] = make_uint4(w[0], w[1], w[2], w[3]);
    }
    // w3 bf16 -> transposed fp32 LDS
    {
        const unsigned int* w3u = (const unsigned int*)(st + (size_t)(bi * 1024 + f * 32 + g) * 4672 + R2c);
        for (int i = t; i < 1024; i += NTHREADS) {
            unsigned int u = w3u[i];
            int e0 = 2*i;
            int oc = e0 >> 6, ch = e0 & 63;
            w3T[ch*33 + oc]     = bf16lo_to_f(u);
            w3T[(ch+1)*33 + oc] = bf16hi_to_f(u);
        }
    }
    __syncthreads();

    const int og3 = t >> 4, pg = t & 15;
    const ushort* zhu = (const ushort*)zh_f;
    float o3[2][4];
    #pragma unroll
    for (int i = 0; i < 2; i++)
        #pragma unroll
        for (int k = 0; k < 4; k++) o3[i][k] = 0.f;
    #pragma unroll 4
    for (int ch = 0; ch < 64; ch++) {
        uint2 zz = *(const uint2*)(zhu + ch*64 + pg*4);
        float z0 = bf16lo_to_f(zz.x), z1 = bf16hi_to_f(zz.x);
        float z2 = bf16lo_to_f(zz.y), z3 = bf16hi_to_f(zz.y);
        float w0  = w3T[ch*33 + og3*2];
        float w1v = w3T[ch*33 + og3*2 + 1];
        o3[0][0] += w0*z0;  o3[0][1] += w0*z1;  o3[0][2] += w0*z2;  o3[0][3] += w0*z3;
        o3[1][0] += w1v*z0; o3[1][1] += w1v*z1; o3[1][2] += w1v*z2; o3[1][3] += w1v*z3;
    }

    // stats3
    #pragma unroll
    for (int i = 0; i < 2; i++) {
        float sm = o3[i][0] + o3[i][1] + o3[i][2] + o3[i][3];
        float qq = o3[i][0]*o3[i][0] + o3[i][1]*o3[i][1] + o3[i][2]*o3[i][2] + o3[i][3]*o3[i][3];
        #pragma unroll
        for (int m = 8; m >= 1; m >>= 1) { sm += __shfl_xor(sm, m); qq += __shfl_xor(qq, m); }
        if (pg == 0) {
            atomicAdd(&ws[SLOTS3  + (og3*2 + i)*64 + slot], sm);
            atomicAdd(&ws[SLOTS3Q + (og3*2 + i)*64 + slot], qq);
        }
    }
    // store o bf16 [patch][32][64]
    ushort* op = obuf + (size_t)blk * 2048;
    #pragma unroll
    for (int i = 0; i < 2; i++) {
        uint2 pk;
        pk.x = pack_bf16(o3[i][0], o3[i][1]);
        pk.y = pack_bf16(o3[i][2], o3[i][3]);
        *(uint2*)(op + (og3*2 + i)*64 + pg*4) = pk;
    }
}

// ---------------------------------------------------------------------------
// K4: out = x + bn3(o), vectorized x4.
__global__ __launch_bounds__(NTHREADS)
void k4_read4(const float* __restrict__ x, const float* __restrict__ ws,
              const ushort* __restrict__ obuf, float* __restrict__ out) {
    size_t idx = (size_t)blockIdx.x * NTHREADS + threadIdx.x;
    size_t e = idx * 4;
    int wq = (int)(e & 255);
    int h  = (int)((e >> 8) & 255);
    int oc = (int)((e >> 16) & 31);
    int bi = (int)(e >> 21);
    float a3 = ws[FIN3 + oc], b3c = ws[FIN3 + 32 + oc];
    int blk = (bi << 10) | ((h >> 3) << 5) | (wq >> 3);
    int pix = ((h & 7) << 3) | (wq & 7);
    uint2 ov = *(const uint2*)(obuf + (size_t)blk * 2048 + oc*64 + pix);
    float4 xv = *(const float4*)(x + e);
    float4 r;
    r.x = xv.x + bf16lo_to_f(ov.x)*a3 + b3c;
    r.y = xv.y + bf16hi_to_f(ov.x)*a3 + b3c;
    r.z = xv.z + bf16lo_to_f(ov.y)*a3 + b3c;
    r.w = xv.w + bf16hi_to_f(ov.y)*a3 + b3c;
    *(float4*)(out + e) = r;
}

// ---------------------------------------------------------------------------
// ===== OLD fallback kernels (round-3 behavior, unchanged) =====
__global__ __launch_bounds__(256)
void transpose_s(const float* __restrict__ s, float* __restrict__ st) {
    __shared__ float tile[32][33];
    const int bi = blockIdx.z;
    const int p0 = blockIdx.x * 32;
    const int q0 = blockIdx.y * 32;
    const int tx = threadIdx.x;
    const int ty = threadIdx.y;
    const float* sb = s + (size_t)bi * 4672 * 1024;
    float* stb = st + (size_t)bi * 1024 * 4672;
    #pragma unroll
    for (int r = ty; r < 32; r += 8)
        tile[r][tx] = sb[(size_t)(p0 + r) * 1024 + q0 + tx];
    __syncthreads();
    #pragma unroll
    for (int r = ty; r < 32; r += 8)
        stb[(size_t)(q0 + r) * 4672 + p0 + tx] = tile[tx][r];
}

__global__ __launch_bounds__(NTHREADS)
void k1_stats(const float* __restrict__ x, const float* __restrict__ s,
              const float* __restrict__ st, float* __restrict__ ws) {
    __shared__ float A[5248];
    const int t = threadIdx.x, blk = blockIdx.x;
    const int bi = blk >> 10, f = (blk >> 5) & 31, g = blk & 31, slot = blk & 63;

    const float* xb = x + (size_t)bi * Cc * Hh * Hh;
    for (int i = t; i < 3200; i += NTHREADS) {
        int c = i / 100;
        int rem = i - c * 100;
        int pr = rem / 10, pc = rem - pr * 10;
        int row = f * PHc - 1 + pr; row = row < 0 ? -row : (row > 255 ? 510 - row : row);
        int col = g * PHc - 1 + pc; col = col < 0 ? -col : (col > 255 ? 510 - col : col);
        A[i] = xb[(size_t)c * 65536 + row * 256 + col];
    }
    if (st) {
        const float4* w4 = (const float4*)(st + (size_t)(bi * 1024 + f * 32 + g) * 4672);
        float4* a4 = (float4*)(A + 3200);
        for (int i = t; i < 512; i += NTHREADS) a4[i] = w4[i];
    } else {
        const float* wp = s + (size_t)bi * 4672 * 1024 + f * 32 + g;
        for (int i = t; i < 2048; i += NTHREADS) A[3200 + i] = wp[(size_t)i * 1024];
    }
    __syncthreads();

    const int og = t >> 5, pl = t & 31;
    float acc[8][4];
    #pragma unroll
    for (int i = 0; i < 8; i++) { acc[i][0]=0.f; acc[i][1]=0.f; acc[i][2]=0.f; acc[i][3]=0.f; }
    #pragma unroll 4
    for (int c = 0; c < 32; c++) {
        float xa0 = A[c*100 + pl];
        float xa1 = A[c*100 + pl + 32];
        float xa2 = A[c*100 + pl + 64];
        float xa3 = A[c*100 + pl + 96];
        const float* wrow = &A[3200 + og*256 + c];
        #pragma unroll
        for (int i = 0; i < 8; i++) {
            float wv = wrow[i*32];
            acc[i][0] += wv * xa0; acc[i][1] += wv * xa1;
            acc[i][2] += wv * xa2; acc[i][3] += wv * xa3;
        }
    }
    #pragma unroll
    for (int i = 0; i < 8; i++) {
        float a3v = (pl < 4) ? acc[i][3] : 0.f;
        float sm = acc[i][0] + acc[i][1] + acc[i][2] + a3v;
        float qq = acc[i][0]*acc[i][0] + acc[i][1]*acc[i][1] + acc[i][2]*acc[i][2] + a3v*a3v;
        #pragma unroll
        for (int m = 16; m >= 1; m >>= 1) { sm += __shfl_xor(sm, m); qq += __shfl_xor(qq, m); }
        if (pl == 0) {
            atomicAdd(&ws[SLOTS1  + (og*8 + i)*64 + slot], sm);
            atomicAdd(&ws[SLOTS1Q + (og*8 + i)*64 + slot], qq);
        }
    }
}

__global__ __launch_bounds__(NTHREADS)
void k2_store(const float* __restrict__ x, const float* __restrict__ st,
              ushort* __restrict__ zbuf, float* __restrict__ ws) {
    __shared__ float xy[3840];
    __shared__ float w1s[2048];
    __shared__ float fin_s[128];

    const int t = threadIdx.x, blk = blockIdx.x;
    const int bi = blk >> 10, f = (blk >> 5) & 31, g = blk & 31, slot = blk & 63;

    const float* xb = x + (size_t)bi * Cc * Hh * Hh;
    for (int i = t; i < 3200; i += NTHREADS) {
        int c = i / 100;
        int rem = i - c * 100;
        int pr = rem / 10, pc = rem - pr * 10;
        int row = f * PHc - 1 + pr; row = row < 0 ? -row : (row > 255 ? 510 - row : row);
        int col = g * PHc - 1 + pc; col = col < 0 ? -col : (col > 255 ? 510 - col : col);
        xy[i] = xb[(size_t)c * 65536 + row * 256 + col];
    }
    const float* wp = st + (size_t)(bi * 1024 + f * 32 + g) * 4672;
    {
        const float4* w4 = (const float4*)wp;
        float4* a4 = (float4*)w1s;
        for (int i = t; i < 512; i += NTHREADS) a4[i] = w4[i];
    }
    float w2r0 = wp[R1c + t];
    float w2r1 = wp[R1c + 256 + t];
    float w2r2 = (t < 64) ? wp[R1c + 512 + t] : 0.f;
    if (t < 128) fin_s[t] = ws[FIN1 + t];
    __syncthreads();

    const int og = t >> 5, pl = t & 31;
    float acc[8][4];
    #pragma unroll
    for (int i = 0; i < 8; i++) { acc[i][0]=0.f; acc[i][1]=0.f; acc[i][2]=0.f; acc[i][3]=0.f; }
    #pragma unroll 4
    for (int c = 0; c < 32; c++) {
        float xa0 = xy[c*100 + pl];
        float xa1 = xy[c*100 + pl + 32];
        float xa2 = xy[c*100 + pl + 64];
        float xa3 = xy[c*100 + pl + 96];
        const float* wrow = &w1s[og*256 + c];
        #pragma unroll
        for (int i = 0; i < 8; i++) {
            float wv = wrow[i*32];
            acc[i][0] += wv * xa0; acc[i][1] += wv * xa1;
            acc[i][2] += wv * xa2; acc[i][3] += wv * xa3;
        }
    }
    __syncthreads();

    ushort* yb = (ushort*)xy;
    #pragma unroll
    for (int i = 0; i < 8; i++) {
        int ch = og*8 + i;
        float a1 = fin_s[ch], b1 = fin_s[64 + ch];
        #pragma unroll
        for (int k = 0; k < 4; k++) {
            int p = pl + k*32;
            if (k < 3 || pl < 4) {
                float v = fminf(fmaxf(acc[i][k]*a1 + b1, 0.f), 6.f);
                int row = p / 10, col = p - row*10;
                yb[ch*120 + row*12 + col] = f_to_bf16(v);
            }
        }
    }
    w1s[t] = w2r0;
    w1s[256 + t] = w2r1;
    if (t < 64) w1s[512 + t] = w2r2;
    __syncthreads();

    const int ch2 = t >> 2, quad = t & 3, p0 = quad * 2;
    const unsigned int* yu = (const unsigned int*)xy;
    float yr[4][10];
    #pragma unroll
    for (int r = 0; r < 4; r++) {
        int base = ch2*60 + (p0 + r)*6;
        #pragma unroll
        for (int k = 0; k < 5; k++) {
            unsigned int u = yu[base + k];
            yr[r][2*k]   = bf16lo_to_f(u);
            yr[r][2*k+1] = bf16hi_to_f(u);
        }
    }
    float zacc[2][8];
    #pragma unroll
    for (int pr = 0; pr < 2; pr++)
        #pragma unroll
        for (int q = 0; q < 8; q++) zacc[pr][q] = 0.f;
    #pragma unroll
    for (int u = 0; u < 3; u++)
        #pragma unroll
        for (int v = 0; v < 3; v++) {
            float wv = w1s[ch2*9 + u*3 + v];
            #pragma unroll
            for (int pr = 0; pr < 2; pr++)
                #pragma unroll
                for (int q = 0; q < 8; q++)
                    zacc[pr][q] += wv * yr[pr + u][q + v];
        }
    float zs = 0.f, zq = 0.f;
    #pragma unroll
    for (int pr = 0; pr < 2; pr++)
        #pragma unroll
        for (int q = 0; q < 8; q++) { float v = zacc[pr][q]; zs += v; zq += v*v; }
    zs += __shfl_xor(zs, 1); zs += __shfl_xor(zs, 2);
    zq += __shfl_xor(zq, 1); zq += __shfl_xor(zq, 2);
    if (quad == 0) {
        atomicAdd(&ws[SLOTS2  + ch2*64 + slot], zs);
        atomicAdd(&ws[SLOTS2Q + ch2*64 + slot], zq);
    }
    ushort* zp = zbuf + (size_t)blk * 4096;
    #pragma unroll
    for (int pr = 0; pr < 2; pr++) {
        uint4 pk;
        pk.x = pack_bf16(zacc[pr][0], zacc[pr][1]);
        pk.y = pack_bf16(zacc[pr][2], zacc[pr][3]);
        pk.z = pack_bf16(zacc[pr][4], zacc[pr][5]);
        pk.w = pack_bf16(zacc[pr][6], zacc[pr][7]);
        *(uint4*)(zp + ch2*64 + (p0 + pr)*8) = pk;
    }
}

template<int WRITE_OUT>
__global__ __launch_bounds__(NTHREADS)
void k3_k(const float* __restrict__ x, const ushort* __restrict__ zbuf,
          const float* __restrict__ st, float* __restrict__ ws,
          float* __restrict__ out) {
    __shared__ float zh_f[2048];
    __shared__ float w3T[2112];

    const int t = threadIdx.x, blk = blockIdx.x;
    const int bi = blk >> 10, f = (blk >> 5) & 31, g = blk & 31, slot = blk & 63;

    const uint4* zsrc = (const uint4*)(zbuf + (size_t)blk * 4096);
    uint4* zdst = (uint4*)zh_f;
    for (int i = t; i < 512; i += NTHREADS) {
        uint4 v = zsrc[i];
        int ch = i >> 3;
        float a2 = ws[FIN2 + ch], b2 = ws[FIN2 + 64 + ch];
        unsigned int w[4] = {v.x, v.y, v.z, v.w};
        #pragma unroll
        for (int k = 0; k < 4; k++) {
            float lo = fminf(fmaxf(bf16lo_to_f(w[k])*a2 + b2, 0.f), 6.f);
            float hi = fminf(fmaxf(bf16hi_to_f(w[k])*a2 + b2, 0.f), 6.f);
            w[k] = pack_bf16(lo, hi);
        }
        zdst[i] = make_uint4(w[0], w[1], w[2], w[3]);
    }
    const float* wp = st + (size_t)(bi * 1024 + f * 32 + g) * 4672;
    for (int i = t; i < 2048; i += NTHREADS)
        w3T[(i & 63)*33 + (i >> 6)] = wp[R2c + i];
    __syncthreads();

    const int og3 = t >> 4, pg = t & 15;
    const ushort* zhu = (const ushort*)zh_f;
    float o3[2][4];
    #pragma unroll
    for (int i = 0; i < 2; i++)
        #pragma unroll
        for (int k = 0; k < 4; k++) o3[i][k] = 0.f;
    #pragma unroll 4
    for (int ch = 0; ch < 64; ch++) {
        uint2 zz = *(const uint2*)(zhu + ch*64 + pg*4);
        float z0 = bf16lo_to_f(zz.x), z1 = bf16hi_to_f(zz.x);
        float z2 = bf16lo_to_f(zz.y), z3 = bf16hi_to_f(zz.y);
        float w0  = w3T[ch*33 + og3*2];
        float w1v = w3T[ch*33 + og3*2 + 1];
        o3[0][0] += w0*z0;  o3[0][1] += w0*z1;  o3[0][2] += w0*z2;  o3[0][3] += w0*z3;
        o3[1][0] += w1v*z0; o3[1][1] += w1v*z1; o3[1][2] += w1v*z2; o3[1][3] += w1v*z3;
    }

    if (!WRITE_OUT) {
        #pragma unroll
        for (int i = 0; i < 2; i++) {
            float sm = o3[i][0] + o3[i][1] + o3[i][2] + o3[i][3];
            float qq = o3[i][0]*o3[i][0] + o3[i][1]*o3[i][1] + o3[i][2]*o3[i][2] + o3[i][3]*o3[i][3];
            #pragma unroll
            for (int m = 8; m >= 1; m >>= 1) { sm += __shfl_xor(sm, m); qq += __shfl_xor(qq, m); }
            if (pg == 0) {
                atomicAdd(&ws[SLOTS3  + (og3*2 + i)*64 + slot], sm);
                atomicAdd(&ws[SLOTS3Q + (og3*2 + i)*64 + slot], qq);
            }
        }
    } else {
        #pragma unroll
        for (int i = 0; i < 2; i++) {
            int oc = og3*2 + i;
            float a3 = ws[FIN3 + oc], b3c = ws[FIN3 + 32 + oc];
            int p = pg >> 1, q0c = (pg & 1) * 4;
            size_t oidx = ((size_t)((bi*32 + oc)*256 + f*8 + p))*256 + g*8 + q0c;
            float4 xv = *(const float4*)(x + oidx);
            float4 v4 = make_float4(xv.x + o3[i][0]*a3 + b3c,
                                    xv.y + o3[i][1]*a3 + b3c,
                                    xv.z + o3[i][2]*a3 + b3c,
                                    xv.w + o3[i][3]*a3 + b3c);
            *(float4*)(out + oidx) = v4;
        }
    }
}

__global__ void finalize_k(float* __restrict__ ws, int stage,
                           const float* __restrict__ gamma, const float* __restrict__ beta) {
    int ch = threadIdx.x;
    int nch = (stage == 3) ? 32 : 64;
    if (ch >= nch) return;
    int so = (stage == 1) ? SLOTS1  : (stage == 2) ? SLOTS2  : SLOTS3;
    int sq = (stage == 1) ? SLOTS1Q : (stage == 2) ? SLOTS2Q : SLOTS3Q;
    int fo = (stage == 1) ? FIN1    : (stage == 2) ? FIN2    : FIN3;
    float N = (stage == 1) ? 819200.0f : 524288.0f;
    float sm = 0.f, qq = 0.f;
    for (int j = 0; j < 64; j++) { sm += ws[so + ch*64 + j]; qq += ws[sq + ch*64 + j]; }
    float mean = sm / N;
    float var  = qq / N - mean * mean;
    float rstd = rsqrtf(var + EPSc);
    float a = rstd * gamma[ch];
    ws[fo + ch]       = a;
    ws[fo + nch + ch] = beta[ch] - mean * a;
}

// ---------------------------------------------------------------------------
extern "C" void kernel_launch(void* const* d_in, const int* in_sizes, int n_in,
                              void* d_out, int out_size, void* d_ws, size_t ws_size,
                              hipStream_t stream) {
    const float* x  = (const float*)d_in[0];
    const float* s  = (const float*)d_in[1];
    const float* g1 = (const float*)d_in[2];
    const float* b1 = (const float*)d_in[3];
    const float* g2 = (const float*)d_in[4];
    const float* b2 = (const float*)d_in[5];
    const float* g3 = (const float*)d_in[6];
    const float* b3 = (const float*)d_in[7];
    float* out = (float*)d_out;
    float* ws  = (float*)d_ws;

    hipMemsetAsync(d_ws, 0, STATS_ZERO_FLOATS * sizeof(float), stream);

    if (ws_size >= NEED_NEW2) {
        ushort* st2 = (ushort*)((char*)d_ws + ST2_BYTE_OFF);
        ushort* yb  = (ushort*)((char*)d_ws + Y_BYTE_OFF);
        ushort* zb  = (ushort*)((char*)d_ws + Z2_BYTE_OFF);
        ushort* ob  = (ushort*)((char*)d_ws + O_BYTE_OFF);
        transpose_s_bf16<<<dim3(146, 32, 8), dim3(32, 8), 0, stream>>>(s, st2);
        k1_store<<<8192, NTHREADS, 0, stream>>>(x, st2, yb, ws);
        finalize_k<<<1, 64, 0, stream>>>(ws, 1, g1, b1);
        k2_bn1dw<<<8192, NTHREADS, 0, stream>>>(yb, st2, zb, ws);
        finalize_k<<<1, 64, 0, stream>>>(ws, 2, g2, b2);
        k3_stats_store<<<8192, NTHREADS, 0, stream>>>(zb, st2, ob, ws);
        finalize_k<<<1, 64, 0, stream>>>(ws, 3, g3, b3);
        k4_read4<<<16384, NTHREADS, 0, stream>>>(x, ws, ob, out);
        return;
    }

    // fallback: round-3 fast path (fp32 st + z bf16), needs ~220 MB
    {
        float*  st   = ws + ST_OFF;
        ushort* zbuf = (ushort*)((char*)d_ws + Z_BYTE_OFF);
        transpose_s<<<dim3(146, 32, 8), dim3(32, 8), 0, stream>>>(s, st);
        k1_stats<<<8192, NTHREADS, 0, stream>>>(x, s, st, ws);
        finalize_k<<<1, 64, 0, stream>>>(ws, 1, g1, b1);
        k2_store<<<8192, NTHREADS, 0, stream>>>(x, st, zbuf, ws);
        finalize_k<<<1, 64, 0, stream>>>(ws, 2, g2, b2);
        k3_k<0><<<8192, NTHREADS, 0, stream>>>(x, zbuf, st, ws, out);
        finalize_k<<<1, 64, 0, stream>>>(ws, 3, g3, b3);
        k3_k<1><<<8192, NTHREADS, 0, stream>>>(x, zbuf, st, ws, out);
    }
}